// Round 22
// baseline (303.244 us; speedup 1.0000x reference)
//
#include <hip/hip_runtime.h>
#include <hip/hip_bf16.h>
#include <math.h>

// Problem constants
static constexpr int BB = 4;
static constexpr int TT = 1024;
static constexpr int HH = 1024;
static constexpr int NHD = 4;
static constexpr int KDIM = 512;
static constexpr int VDIM = 1024;
static constexpr int DKH = 128;   // KD / NH
static constexpr int DVH = 256;   // VD / NH
static constexpr int RR = 32;
static constexpr int R5D = 160;
static constexpr int GG = 64;
static constexpr int NTOK = BB * TT;   // 4096
static constexpr int CK = 32;          // chunk length
static constexpr int NCK = TT / CK;    // 32 chunks per sequence
static constexpr int WKS = 8;          // split-K factor for the w1 gemm

typedef __bf16 bf16x8 __attribute__((ext_vector_type(8)));
typedef float f32x4 __attribute__((ext_vector_type(4)));
typedef __hip_bfloat16 bf16;

static __device__ inline unsigned short f2u(float v) {
    __hip_bfloat16 b = __float2bfloat16(v);
    unsigned short u; __builtin_memcpy(&u, &b, 2); return u;
}
static __device__ inline float u2f(unsigned short u) {
    __hip_bfloat16 b; __builtin_memcpy(&b, &u, 2); return __bfloat162float(b);
}

// ---------------------------------------------------------------------------
// Kernel 1 (k_pre): f2b2 weight conversion (blocks 64..2111) MERGED with
// x1mm MFMA phase-1 (blocks 0..63). Independent work, disjoint outputs.
// ---------------------------------------------------------------------------
__global__ __launch_bounds__(256) void k_pre(
    const float* __restrict__ h, const float* __restrict__ mu,
    const float* __restrict__ w1, float* __restrict__ t0,
    const float* __restrict__ r_w, const float* __restrict__ k_w,
    const float* __restrict__ v_w, const float* __restrict__ g_w,
    const float* __restrict__ o_w,
    bf16* __restrict__ rh, bf16* __restrict__ rl,
    bf16* __restrict__ kh, bf16* __restrict__ kl,
    bf16* __restrict__ vh, bf16* __restrict__ vl,
    bf16* __restrict__ gh, bf16* __restrict__ gl,
    bf16* __restrict__ oh, bf16* __restrict__ ol)
{
    __shared__ unsigned short Al[64][40];
    __shared__ unsigned short Bl[32][40];
    int tid = threadIdx.x;
    if (blockIdx.x >= 64) {
        // ---- f2b2 path ----
        size_t g = ((size_t)(blockIdx.x - 64) * 256 + tid) * 8;
        const float* s; bf16 *hi, *lo; size_t off;
        if (g < 524288)       { s = r_w; hi = rh; lo = rl; off = g; }
        else if (g < 1048576) { s = k_w; hi = kh; lo = kl; off = g - 524288; }
        else if (g < 2097152) { s = v_w; hi = vh; lo = vl; off = g - 1048576; }
        else if (g < 3145728) { s = g_w; hi = gh; lo = gl; off = g - 2097152; }
        else                  { s = o_w; hi = oh; lo = ol; off = g - 3145728; }
        #pragma unroll
        for (int j = 0; j < 8; j++) {
            float v = s[off + j];
            bf16 hb = __float2bfloat16(v);
            hi[off + j] = hb;
            lo[off + j] = __float2bfloat16(v - __bfloat162float(hb));
        }
        return;
    }
    // ---- x1mm path ----
    int m0 = blockIdx.x * 64;
    int lane = tid & 63, w = tid >> 6;
    f32x4 acc[2];
    acc[0] = (f32x4){0.f, 0.f, 0.f, 0.f};
    acc[1] = (f32x4){0.f, 0.f, 0.f, 0.f};
    int ar = tid >> 2, ac0 = (tid & 3) * 8;        // A stage: 64x32, 8 per thread
    int br = tid >> 3, bc0 = (tid & 7) * 4;        // B stage: 32x32, 4 per thread
    int fr = lane & 15, kb = lane >> 4;
    int mrow = m0 + ar;
    int trow = mrow & (TT - 1);
    const float* hp = h + (size_t)mrow * HH;
    for (int k0 = 0; k0 < HH; k0 += 32) {
        float av[8];
        #pragma unroll
        for (int j = 0; j < 8; j += 4) {
            float4 c4 = *(const float4*)(hp + k0 + ac0 + j);
            float4 p4 = make_float4(0.f, 0.f, 0.f, 0.f);
            if (trow > 0) p4 = *(const float4*)(hp + k0 + ac0 + j - HH);
            float4 m4 = *(const float4*)(mu + k0 + ac0 + j);
            av[j + 0] = c4.x + (p4.x - c4.x) * m4.x;
            av[j + 1] = c4.y + (p4.y - c4.y) * m4.y;
            av[j + 2] = c4.z + (p4.z - c4.z) * m4.z;
            av[j + 3] = c4.w + (p4.w - c4.w) * m4.w;
        }
        float4 b4 = *(const float4*)(w1 + (size_t)br * HH + k0 + bc0);
        __syncthreads();
        #pragma unroll
        for (int j = 0; j < 8; j++) Al[ar][ac0 + j] = f2u(av[j]);
        Bl[br][bc0 + 0] = f2u(b4.x); Bl[br][bc0 + 1] = f2u(b4.y);
        Bl[br][bc0 + 2] = f2u(b4.z); Bl[br][bc0 + 3] = f2u(b4.w);
        __syncthreads();
        bf16x8 af = *(const bf16x8*)(&Al[w * 16 + fr][kb * 8]);
        bf16x8 bf0 = *(const bf16x8*)(&Bl[fr][kb * 8]);
        bf16x8 bf1 = *(const bf16x8*)(&Bl[16 + fr][kb * 8]);
        acc[0] = __builtin_amdgcn_mfma_f32_16x16x32_bf16(af, bf0, acc[0], 0, 0, 0);
        acc[1] = __builtin_amdgcn_mfma_f32_16x16x32_bf16(af, bf1, acc[1], 0, 0, 0);
    }
    int er = (lane >> 4) * 4, ec = lane & 15;
    #pragma unroll
    for (int j = 0; j < 2; j++) {
        #pragma unroll
        for (int q = 0; q < 4; q++) {
            int gr = m0 + w * 16 + er + q;
            t0[(size_t)gr * RR + j * 16 + ec] = tanhf(acc[j][q]);
        }
    }
}

// ---------------------------------------------------------------------------
// Kernel 1b (k_x1b): x1[4096x160] = tanh( t0 @ w2^T + b2 ).  K=32.
// ---------------------------------------------------------------------------
__global__ __launch_bounds__(256) void k_x1b(
    const float* __restrict__ t0, const float* __restrict__ w2,
    const float* __restrict__ b2, float* __restrict__ x1out)
{
    __shared__ float t0s[64][33];
    __shared__ float w2s[R5D * RR];
    __shared__ float b2s[R5D];
    int tid = threadIdx.x;
    int m0 = blockIdx.x * 64;
    {
        int row = tid >> 2, c0 = (tid & 3) * 8;
        float4 a = *(const float4*)(t0 + (size_t)(m0 + row) * RR + c0);
        float4 b = *(const float4*)(t0 + (size_t)(m0 + row) * RR + c0 + 4);
        t0s[row][c0 + 0] = a.x; t0s[row][c0 + 1] = a.y;
        t0s[row][c0 + 2] = a.z; t0s[row][c0 + 3] = a.w;
        t0s[row][c0 + 4] = b.x; t0s[row][c0 + 5] = b.y;
        t0s[row][c0 + 6] = b.z; t0s[row][c0 + 7] = b.w;
    }
    for (int i = tid; i < R5D * RR; i += 256) w2s[i] = w2[i];
    if (tid < R5D) b2s[tid] = b2[tid];
    __syncthreads();
    int tt = tid & 63, cg = tid >> 6;
    float t0r[32];
    #pragma unroll
    for (int q = 0; q < 32; q++) t0r[q] = t0s[tt][q];
    float* xo = x1out + (size_t)(m0 + tt) * R5D + cg * 40;
    for (int c = 0; c < 40; c++) {
        const float* wr = w2s + (cg * 40 + c) * RR;
        float s = b2s[cg * 40 + c];
        #pragma unroll
        for (int q = 0; q < 32; q++) s += t0r[q] * wr[q];
        xo[c] = tanhf(s);
    }
}

// ---------------------------------------------------------------------------
// Kernel 2 (k_mix): mixw (even x-blocks) MERGED with mix4 (odd x-blocks).
// Same bodies as the standalone kernels; x-parity interleave co-schedules
// mixw's memory-heavy phase with mix4's MFMA phase.
// ---------------------------------------------------------------------------
__global__ __launch_bounds__(256) void k_mix(
    const float* __restrict__ h, const float* __restrict__ x1,
    const float* __restrict__ xow, const float* __restrict__ xb,
    float* __restrict__ xw, bf16* __restrict__ xr,
    bf16* __restrict__ xk, bf16* __restrict__ xv, bf16* __restrict__ xg)
{
    __shared__ float x1sT[32][68];
    __shared__ float xosT[32][68];
    int m0 = (blockIdx.x >> 1) * 64;
    int h0 = blockIdx.y * 64;
    int tid = threadIdx.x;
    if ((blockIdx.x & 1) == 0) {
        // ---- mixw path (n=1 slice, f32 exact) ----
        int rr = tid & 63, cg = tid >> 6;    // cg = wave id, 8 cols each
        {
            const float* xp = x1 + (size_t)(m0 + rr) * R5D + 32 + cg * 8;
            const float* wp = xow + (size_t)(h0 + rr) * R5D + 32 + cg * 8;
            float4 a0 = *(const float4*)xp, a1 = *(const float4*)(xp + 4);
            float4 b0 = *(const float4*)wp, b1 = *(const float4*)(wp + 4);
            x1sT[cg * 8 + 0][rr] = a0.x; x1sT[cg * 8 + 1][rr] = a0.y;
            x1sT[cg * 8 + 2][rr] = a0.z; x1sT[cg * 8 + 3][rr] = a0.w;
            x1sT[cg * 8 + 4][rr] = a1.x; x1sT[cg * 8 + 5][rr] = a1.y;
            x1sT[cg * 8 + 6][rr] = a1.z; x1sT[cg * 8 + 7][rr] = a1.w;
            xosT[cg * 8 + 0][rr] = b0.x; xosT[cg * 8 + 1][rr] = b0.y;
            xosT[cg * 8 + 2][rr] = b0.z; xosT[cg * 8 + 3][rr] = b0.w;
            xosT[cg * 8 + 4][rr] = b1.x; xosT[cg * 8 + 5][rr] = b1.y;
            xosT[cg * 8 + 6][rr] = b1.z; xosT[cg * 8 + 7][rr] = b1.w;
        }
        int tx = tid & 15, ty = tid >> 4;
        float creg[4][4], dreg[4][4];
        #pragma unroll
        for (int i = 0; i < 4; i++) {
            int m = m0 + ty * 4 + i;
            int t = m & (TT - 1);
            const float* hp = h + (size_t)m * HH + h0 + tx * 4;
            float4 c4 = *(const float4*)hp;
            float4 p4 = make_float4(0.f, 0.f, 0.f, 0.f);
            if (t > 0) p4 = *(const float4*)(hp - HH);
            creg[i][0] = c4.x; dreg[i][0] = p4.x - c4.x;
            creg[i][1] = c4.y; dreg[i][1] = p4.y - c4.y;
            creg[i][2] = c4.z; dreg[i][2] = p4.z - c4.z;
            creg[i][3] = c4.w; dreg[i][3] = p4.w - c4.w;
        }
        __syncthreads();
        float acc[4][4] = {};
        #pragma unroll
        for (int r2 = 0; r2 < 32; r2++) {
            float4 a4 = *(const float4*)&x1sT[r2][ty * 4];
            float4 b4 = *(const float4*)&xosT[r2][tx * 4];
            float aa[4] = {a4.x, a4.y, a4.z, a4.w};
            float bb[4] = {b4.x, b4.y, b4.z, b4.w};
            #pragma unroll
            for (int i = 0; i < 4; i++)
                #pragma unroll
                for (int j = 0; j < 4; j++)
                    acc[i][j] += aa[i] * bb[j];
        }
        float4 xb4 = *(const float4*)(xb + HH + h0 + tx * 4);   // n=1 row
        float xbv[4] = {xb4.x, xb4.y, xb4.z, xb4.w};
        #pragma unroll
        for (int i = 0; i < 4; i++) {
            size_t idx = (size_t)(m0 + ty * 4 + i) * HH + h0 + tx * 4;
            float v[4];
            #pragma unroll
            for (int j = 0; j < 4; j++)
                v[j] = creg[i][j] + dreg[i][j] * (acc[i][j] + xbv[j]);
            *(float4*)(xw + idx) = make_float4(v[0], v[1], v[2], v[3]);
        }
        return;
    }
    // ---- mix4 path (n in {0,2,3,4}, bf16 MFMA) ----
    int lane = tid & 63, w = tid >> 6;
    int fr = lane & 15, kb = (lane >> 4) * 8;
    int er = (lane >> 4) * 4, ec = lane & 15;
    float creg[4][4], dreg[4][4];
    #pragma unroll
    for (int q = 0; q < 4; q++) {
        int m = m0 + w * 16 + er + q;
        int t = m & (TT - 1);
        const float* hp = h + (size_t)m * HH;
        #pragma unroll
        for (int j = 0; j < 4; j++) {
            int hh = h0 + j * 16 + ec;
            float c = hp[hh];
            float p = (t > 0) ? hp[hh - HH] : 0.f;
            creg[q][j] = c;
            dreg[q][j] = p - c;
        }
    }
    bf16* outs[4] = {xr, xk, xv, xg};
    const int ns[4] = {0, 2, 3, 4};
    #pragma unroll
    for (int ni = 0; ni < 4; ni++) {
        int n = ns[ni];
        const float* ap = x1 + (size_t)(m0 + w * 16 + fr) * R5D + n * 32 + kb;
        float4 a0 = *(const float4*)ap;
        float4 a1 = *(const float4*)(ap + 4);
        alignas(16) unsigned short ta[8];
        ta[0] = f2u(a0.x); ta[1] = f2u(a0.y); ta[2] = f2u(a0.z); ta[3] = f2u(a0.w);
        ta[4] = f2u(a1.x); ta[5] = f2u(a1.y); ta[6] = f2u(a1.z); ta[7] = f2u(a1.w);
        bf16x8 af = *(const bf16x8*)ta;
        f32x4 accj[4];
        #pragma unroll
        for (int j = 0; j < 4; j++) {
            const float* bp = xow + (size_t)(h0 + j * 16 + fr) * R5D + n * 32 + kb;
            float4 b0 = *(const float4*)bp;
            float4 b1 = *(const float4*)(bp + 4);
            alignas(16) unsigned short tb[8];
            tb[0] = f2u(b0.x); tb[1] = f2u(b0.y); tb[2] = f2u(b0.z); tb[3] = f2u(b0.w);
            tb[4] = f2u(b1.x); tb[5] = f2u(b1.y); tb[6] = f2u(b1.z); tb[7] = f2u(b1.w);
            bf16x8 bf_ = *(const bf16x8*)tb;
            f32x4 z = (f32x4){0.f, 0.f, 0.f, 0.f};
            accj[j] = __builtin_amdgcn_mfma_f32_16x16x32_bf16(af, bf_, z, 0, 0, 0);
        }
        bf16* op = outs[ni];
        #pragma unroll
        for (int j = 0; j < 4; j++) {
            float xbv = xb[n * HH + h0 + j * 16 + ec];
            #pragma unroll
            for (int q = 0; q < 4; q++) {
                float val = creg[q][j] + dreg[q][j] * (accj[j][q] + xbv);
                op[(size_t)(m0 + w * 16 + er + q) * HH + h0 + j * 16 + ec] =
                    __float2bfloat16(val);
            }
        }
    }
}

// ---------------------------------------------------------------------------
// Kernel 3 (k_gemm5): FOUR hi/lo MFMA GEMMs (z 0..3, hl4 structure,
// global_load_lds staging) MERGED with the split-K f32 w1 GEMM (z 4..5).
// w1 is VALU-only, hl4 is MFMA-heavy -> separate pipes co-schedule.
// LDS unioned in one 24 KB buffer.
// ---------------------------------------------------------------------------
__global__ __launch_bounds__(256) void k_gemm5(
    const bf16* __restrict__ A0, const bf16* __restrict__ Bh0,
    const bf16* __restrict__ Bl0, float* __restrict__ C0,
    const bf16* __restrict__ A1, const bf16* __restrict__ Bh1,
    const bf16* __restrict__ Bl1, float* __restrict__ C1,
    const bf16* __restrict__ A2, const bf16* __restrict__ Bh2,
    const bf16* __restrict__ Bl2, float* __restrict__ C2,
    const bf16* __restrict__ A3, const bf16* __restrict__ Bh3,
    const bf16* __restrict__ Bl3, float* __restrict__ C3,
    int M, int K,
    const float* __restrict__ Aw, const float* __restrict__ Bw,
    float* __restrict__ P)
{
    __shared__ __align__(16) char smraw[128 * 32 * 2 * 3];   // 24576 B
    int z = blockIdx.z;
    int tid = threadIdx.x;
    if (z >= 4) {
        // ---- w1 path: split-K f32 GEMM ----
        float (*As)[68] = (float(*)[68])smraw;
        float (*Bs)[68] = (float(*)[68])(smraw + 16 * 68 * sizeof(float));
        int idx = (z - 4) * 256 + blockIdx.y * 32 + blockIdx.x;   // [0,512)
        int bm = (idx & 63) * 64;
        int ks = idx >> 6;
        int kbase = ks * (HH / WKS);       // 128-wide K slice
        int tx = tid & 15, ty = tid >> 4;
        int lr = tid >> 2;
        int lk = (tid & 3) * 4;
        float acc[4][4] = {};
        for (int k0 = 0; k0 < HH / WKS; k0 += 16) {
            float4 av = *(const float4*)(Aw + (size_t)(bm + lr) * HH + kbase + k0 + lk);
            float4 bv = *(const float4*)(Bw + (size_t)lr * HH + kbase + k0 + lk);
            As[lk + 0][lr] = av.x; As[lk + 1][lr] = av.y;
            As[lk + 2][lr] = av.z; As[lk + 3][lr] = av.w;
            Bs[lk + 0][lr] = bv.x; Bs[lk + 1][lr] = bv.y;
            Bs[lk + 2][lr] = bv.z; Bs[lk + 3][lr] = bv.w;
            __syncthreads();
            #pragma unroll
            for (int kk = 0; kk < 16; kk++) {
                float4 a4 = *(const float4*)&As[kk][ty * 4];
                float4 b4 = *(const float4*)&Bs[kk][tx * 4];
                float aa[4] = {a4.x, a4.y, a4.z, a4.w};
                float bb[4] = {b4.x, b4.y, b4.z, b4.w};
                #pragma unroll
                for (int i = 0; i < 4; i++)
                    #pragma unroll
                    for (int j = 0; j < 4; j++)
                        acc[i][j] += aa[i] * bb[j];
            }
            __syncthreads();
        }
        #pragma unroll
        for (int i = 0; i < 4; i++) {
            size_t row = (size_t)ks * NTOK + bm + ty * 4 + i;
            *(float4*)(P + row * GG + tx * 4) =
                make_float4(acc[i][0], acc[i][1], acc[i][2], acc[i][3]);
        }
        return;
    }
    // ---- hl4 path ----
    const bf16* A;
    const bf16* Bh;
    const bf16* Bl;
    float* C;
    int N;
    if (z == 0)      { A = A0; Bh = Bh0; Bl = Bl0; C = C0; N = KDIM; }
    else if (z == 1) { A = A1; Bh = Bh1; Bl = Bl1; C = C1; N = KDIM; }
    else if (z == 2) { A = A2; Bh = Bh2; Bl = Bl2; C = C2; N = VDIM; }
    else             { A = A3; Bh = Bh3; Bl = Bl3; C = C3; N = VDIM; }
    int bn = blockIdx.y * 128;
    if (bn >= N) return;
    unsigned short* As16 = (unsigned short*)smraw;
    unsigned short* Bhs = As16 + 128 * 32;
    unsigned short* Bls = Bhs + 128 * 32;
    int bm = blockIdx.x * 128;
    int lane = tid & 63, w = tid >> 6;
    int wr = w >> 1, wc = w & 1;
    const unsigned short* A16 = (const unsigned short*)A;
    const unsigned short* Bh16 = (const unsigned short*)Bh;
    const unsigned short* Bl16 = (const unsigned short*)Bl;
    f32x4 acc[4][4];
    #pragma unroll
    for (int i = 0; i < 4; i++)
        #pragma unroll
        for (int j = 0; j < 4; j++)
            acc[i][j] = (f32x4){0.f, 0.f, 0.f, 0.f};
    int fr = lane & 15, kb = (lane >> 4) * 8;
    // chunk mapping: chunk c (16B) covers row c>>2, col (c&3)*8 shorts.
    int c0w = w * 128;
    for (int k0 = 0; k0 < K; k0 += 32) {
        #pragma unroll
        for (int q = 0; q < 2; q++) {
            int cb = c0w + q * 64;            // wave-uniform
            int c = cb + lane;
            int row = c >> 2, co = (c & 3) * 8;
            const unsigned short* ga = A16 + (size_t)(bm + row) * K + k0 + co;
            const unsigned short* gh2 = Bh16 + (size_t)(bn + row) * K + k0 + co;
            const unsigned short* gl2 = Bl16 + (size_t)(bn + row) * K + k0 + co;
            __builtin_amdgcn_global_load_lds(
                (const __attribute__((address_space(1))) void*)ga,
                (__attribute__((address_space(3))) void*)(As16 + cb * 8), 16, 0, 0);
            __builtin_amdgcn_global_load_lds(
                (const __attribute__((address_space(1))) void*)gh2,
                (__attribute__((address_space(3))) void*)(Bhs + cb * 8), 16, 0, 0);
            __builtin_amdgcn_global_load_lds(
                (const __attribute__((address_space(1))) void*)gl2,
                (__attribute__((address_space(3))) void*)(Bls + cb * 8), 16, 0, 0);
        }
        __syncthreads();
        bf16x8 af[4], bfh[4], bfl[4];
        #pragma unroll
        for (int i = 0; i < 4; i++) {
            af[i]  = *(const bf16x8*)(As16 + (wr * 64 + i * 16 + fr) * 32 + kb);
            bfh[i] = *(const bf16x8*)(Bhs + (wc * 64 + i * 16 + fr) * 32 + kb);
            bfl[i] = *(const bf16x8*)(Bls + (wc * 64 + i * 16 + fr) * 32 + kb);
        }
        #pragma unroll
        for (int i = 0; i < 4; i++)
            #pragma unroll
            for (int j = 0; j < 4; j++) {
                acc[i][j] = __builtin_amdgcn_mfma_f32_16x16x32_bf16(af[i], bfh[j], acc[i][j], 0, 0, 0);
                acc[i][j] = __builtin_amdgcn_mfma_f32_16x16x32_bf16(af[i], bfl[j], acc[i][j], 0, 0, 0);
            }
        __syncthreads();
    }
    int er = (lane >> 4) * 4, ec = lane & 15;
    #pragma unroll
    for (int i = 0; i < 4; i++) {
        int gr = bm + wr * 64 + i * 16 + er;
        #pragma unroll
        for (int j = 0; j < 4; j++) {
            int gc = bn + wc * 64 + j * 16 + ec;
            #pragma unroll
            for (int q = 0; q < 4; q++)
                C[(size_t)(gr + q) * N + gc] = acc[i][j][q];
        }
    }
}

// ---------------------------------------------------------------------------
// Kernel 3c (k_we): e = exp( tanh(sum_ks P) @ w_w2^T + w_b ).
// ---------------------------------------------------------------------------
__global__ __launch_bounds__(256) void k_we(
    const float* __restrict__ P, const float* __restrict__ w_w2,
    const float* __restrict__ w_b, float* __restrict__ eb)
{
    __shared__ float As[64][65];
    __shared__ float Bs[64][65];
    int tid = threadIdx.x;
    int bm = blockIdx.x * 64, bn = blockIdx.y * 64;
    {
        int r = tid >> 2, c0 = (tid & 3) * 16;
        float s[16];
        #pragma unroll
        for (int j = 0; j < 16; j++) s[j] = 0.f;
        for (int ks = 0; ks < WKS; ks++) {
            const float* pp = P + ((size_t)ks * NTOK + bm + r) * GG + c0;
            #pragma unroll
            for (int j = 0; j < 16; j += 4) {
                float4 v = *(const float4*)(pp + j);
                s[j + 0] += v.x; s[j + 1] += v.y; s[j + 2] += v.z; s[j + 3] += v.w;
            }
        }
        #pragma unroll
        for (int j = 0; j < 16; j++) As[r][c0 + j] = tanhf(s[j]);
        const float* bp = w_w2 + (size_t)(bn + r) * GG + c0;
        #pragma unroll
        for (int j = 0; j < 16; j += 4) {
            float4 v = *(const float4*)(bp + j);
            Bs[r][c0 + j + 0] = v.x; Bs[r][c0 + j + 1] = v.y;
            Bs[r][c0 + j + 2] = v.z; Bs[r][c0 + j + 3] = v.w;
        }
    }
    __syncthreads();
    int tx = tid & 15, ty = tid >> 4;
    float acc[4][4] = {};
    #pragma unroll 8
    for (int kk = 0; kk < GG; kk++) {
        float aa[4], bb[4];
        #pragma unroll
        for (int i = 0; i < 4; i++) aa[i] = As[ty * 4 + i][kk];
        #pragma unroll
        for (int j = 0; j < 4; j++) bb[j] = Bs[tx * 4 + j][kk];
        #pragma unroll
        for (int i = 0; i < 4; i++)
            #pragma unroll
            for (int j = 0; j < 4; j++)
                acc[i][j] += aa[i] * bb[j];
    }
    float4 wb4 = *(const float4*)(w_b + bn + tx * 4);
    float wbv[4] = {wb4.x, wb4.y, wb4.z, wb4.w};
    #pragma unroll
    for (int i = 0; i < 4; i++) {
        float v[4];
        #pragma unroll
        for (int j = 0; j < 4; j++) v[j] = __expf(acc[i][j] + wbv[j]);
        *(float4*)(eb + (size_t)(bm + ty * 4 + i) * KDIM + bn + tx * 4) =
            make_float4(v[0], v[1], v[2], v[3]);
    }
}

// ---------------------------------------------------------------------------
// Kernel 5a (chunkA1): LDS-staged r/k/e; 2-way-parallel cumsum; r~,k~ in place;
// M = (k~ * Dtot)^T v; Dtot out; u fused.
// ---------------------------------------------------------------------------
__global__ __launch_bounds__(256) void k_chunkA1(
    const float* __restrict__ eb, float* __restrict__ rb,
    float* __restrict__ kb, const float* __restrict__ vb,
    const float* __restrict__ bonus, float* __restrict__ ub,
    float* __restrict__ Mb, float* __restrict__ Db)
{
    int bh = blockIdx.x;       // b*NH + h (h fast)
    int ck = blockIdx.y;       // 0..31
    int h = bh & 3, b = bh >> 2;
    int tok0 = b * TT + ck * CK;
    int tid = threadIdx.x;
    __shared__ float Ls[CK][128];
    __shared__ float rs[CK][129];
    __shared__ float kt[CK][129];
    __shared__ float vsm[CK][68];
    __shared__ float Dts[128];
    __shared__ float up[CK][8];
    #pragma unroll
    for (int i = 0; i < 16; i++) {
        int idx = i * 256 + tid;
        int t = idx >> 7, c = idx & 127;
        size_t g = (size_t)(tok0 + t) * KDIM + h * DKH + c;
        Ls[t][c] = eb[g];
        rs[t][c] = rb[g];
        kt[t][c] = kb[g];
    }
    __syncthreads();
    {
        int c = tid & 127, hf = tid >> 7;
        float run = 0.f;
        if (hf) {
            #pragma unroll
            for (int t = 0; t < 16; t++) run += Ls[t][c];
        }
        __syncthreads();    // prefix reads of Ls done before overwrites below
        float bc = bonus[h * DKH + c];
        #pragma unroll
        for (int tt2 = 0; tt2 < 16; tt2++) {
            int t = hf * 16 + tt2;
            size_t g = (size_t)(tok0 + t) * KDIM + h * DKH + c;
            float e = Ls[t][c];
            float rv = rs[t][c];
            float kv = kt[t][c];
            rb[g] = rv * __expf(-run);
            Ls[t][c] = rv * kv * bc;          // bonus partial
            run += e;
            float ks = kv * __expf(run);
            kt[t][c] = ks;
            kb[g] = ks;
        }
        if (hf) {
            float dt = __expf(-run);
            Dts[c] = dt;
            Db[(size_t)(bh * NCK + ck) * 128 + c] = dt;
        }
    }
    __syncthreads();
    {
        int t = tid >> 3, seg = tid & 7;
        float s = 0.f;
        #pragma unroll
        for (int q = 0; q < 16; q++) s += Ls[t][seg * 16 + q];
        up[t][seg] = s;
    }
    __syncthreads();
    if (tid < CK) {
        float s = 0.f;
        #pragma unroll
        for (int q = 0; q < 8; q++) s += up[tid][q];
        ub[(size_t)(tok0 + tid) * NHD + h] = s;
    }
    for (int jb = 0; jb < 4; jb++) {
        {
            int j = tid & 63, r0 = tid >> 6;
            #pragma unroll
            for (int i = 0; i < 8; i++) {
                int s = r0 + 4 * i;
                vsm[s][j] = vb[(size_t)(tok0 + s) * VDIM + h * DVH + jb * 64 + j];
            }
        }
        __syncthreads();
        {
            int kk0 = (tid >> 3) * 4;
            int j0 = (tid & 7) * 8;
            float m[4][8] = {};
            for (int s = 0; s < CK; s++) {
                float4 kv = *(const float4*)&kt[s][kk0];
                float4 v0 = *(const float4*)&vsm[s][j0];
                float4 v1 = *(const float4*)&vsm[s][j0 + 4];
                float ka[4] = {kv.x, kv.y, kv.z, kv.w};
                float va[8] = {v0.x, v0.y, v0.z, v0.w, v1.x, v1.y, v1.z, v1.w};
                #pragma unroll
                for (int i = 0; i < 4; i++)
                    #pragma unroll
                    for (int jj = 0; jj < 8; jj++)
                        m[i][jj] += ka[i] * va[jj];
            }
            #pragma unroll
            for (int i = 0; i < 4; i++) {
                float d = Dts[kk0 + i];
                size_t mb = ((size_t)(bh * NCK + ck) * 128 + kk0 + i) * DVH + jb * 64 + j0;
                *(float4*)(Mb + mb)     = make_float4(m[i][0] * d, m[i][1] * d, m[i][2] * d, m[i][3] * d);
                *(float4*)(Mb + mb + 4) = make_float4(m[i][4] * d, m[i][5] * d, m[i][6] * d, m[i][7] * d);
            }
        }
        __syncthreads();
    }
}

// ---------------------------------------------------------------------------
// Kernel 5b (chunkB): sequential over chunks with register prefetch.
// Coalesced mapping: thread = (k-row via wave id, float4 of j via lane).
// ---------------------------------------------------------------------------
__global__ __launch_bounds__(256) void k_chunkB(
    float* __restrict__ MS, const float* __restrict__ Db)
{
    int bh = blockIdx.x;
    int ks = blockIdx.y;               // 0..31 -> 4-row k group
    int tid = threadIdx.x;
    int k = ks * 4 + (tid >> 6);       // wave-uniform row
    int j0 = (tid & 63) * 4;           // lane-consecutive float4
    float4 S = make_float4(0.f, 0.f, 0.f, 0.f);
    float4 m; float d;
    {
        size_t kb0 = (size_t)(bh * NCK) * 128 + k;
        m = *(const float4*)(MS + kb0 * DVH + j0);
        d = Db[kb0];
    }
    for (int c = 0; c < NCK; c++) {
        size_t kbc = (size_t)(bh * NCK + c) * 128 + k;
        float4 mc = m; float dc = d;
        if (c + 1 < NCK) {
            size_t kbn = (size_t)(bh * NCK + c + 1) * 128 + k;
            m = *(const float4*)(MS + kbn * DVH + j0);
            d = Db[kbn];
        }
        *(float4*)(MS + kbc * DVH + j0) = S;
        S.x = S.x * dc + mc.x;
        S.y = S.y * dc + mc.y;
        S.z = S.z * dc + mc.z;
        S.w = S.w * dc + mc.w;
    }
}

// ---------------------------------------------------------------------------
// Kernel 5c (chunkCG v3, 1024 threads): P = mask(r~ k~^T, diag=u);
// o = P@v + r~@S (f32 regs); groupnorm; silu(g) gate; y f32 IN PLACE over v.
// ---------------------------------------------------------------------------
__global__ __launch_bounds__(1024) void k_chunkCG(
    const float* __restrict__ rb, const float* __restrict__ kb,
    float* __restrict__ vb, const float* __restrict__ ub,
    const float* __restrict__ Sb, const float* __restrict__ gb_,
    const float* __restrict__ gnw, const float* __restrict__ gnb)
{
    int bh = blockIdx.x, ck = blockIdx.y;
    int h = bh & 3, b = bh >> 2;
    int tok0 = b * TT + ck * CK;
    int tid = threadIdx.x;
    __shared__ float rt[CK][128];
    __shared__ float kt[CK][129];
    __shared__ float Ps[CK][33];
    __shared__ float stg[2][16][260];   // v staging (both halves), then S tiles in stg[0]
    #pragma unroll
    for (int i = 0; i < 4; i++) {
        int idx = i * 1024 + tid;
        int t = idx >> 7, c = idx & 127;
        size_t g = (size_t)(tok0 + t) * KDIM + h * DKH + c;
        rt[t][c] = rb[g];
        kt[t][c] = kb[g];
    }
    // stage v [32][256]
    {
        int r = tid >> 5, c0 = (tid & 31) * 8;
        const float* vp = vb + (size_t)(tok0 + r) * VDIM + h * DVH + c0;
        float4 a = *(const float4*)vp;
        float4 b2 = *(const float4*)(vp + 4);
        *(float4*)&stg[r >> 4][r & 15][c0]     = a;
        *(float4*)&stg[r >> 4][r & 15][c0 + 4] = b2;
    }
    __syncthreads();
    // P: 1 entry per thread
    {
        int t = tid >> 5, s = tid & 31;
        float a0 = 0.f;
        for (int k4 = 0; k4 < 128; k4 += 4) {
            float4 a = *(const float4*)&rt[t][k4];
            float4 b0 = *(const float4*)&kt[s][k4];
            a0 += a.x * b0.x + a.y * b0.y + a.z * b0.z + a.w * b0.w;
        }
        float u0 = ub[(size_t)(tok0 + t) * NHD + h];
        Ps[t][s] = (s < t) ? a0 : (s == t ? u0 : 0.f);
    }
    __syncthreads();
    int t0 = (tid >> 6) * 2;           // wave owns tokens t0, t0+1
    int c4 = (tid & 63) * 4;           // 64 lanes x 4 cols = full 256-col row
    float acc[2][4] = {};
    // intra-chunk: P @ v (from LDS)
    for (int s = 0; s < CK; s++) {
        float4 v0 = *(const float4*)&stg[s >> 4][s & 15][c4];
        float p0 = Ps[t0][s], p1 = Ps[t0 + 1][s];
        acc[0][0] += p0 * v0.x; acc[0][1] += p0 * v0.y;
        acc[0][2] += p0 * v0.z; acc[0][3] += p0 * v0.w;
        acc[1][0] += p1 * v0.x; acc[1][1] += p1 * v0.y;
        acc[1][2] += p1 * v0.z; acc[1][3] += p1 * v0.w;
    }
    // inter-chunk: r~ @ S, S tiled through LDS (each S byte read once from L2)
    size_t sbase = (size_t)(bh * NCK + ck) * 128 * DVH;
    int srow = tid >> 6;               // 0..15
    int scol = (tid & 63) * 4;
    float4 rg = *(const float4*)(Sb + sbase + (size_t)srow * DVH + scol);
    for (int tt = 0; tt < 8; tt++) {
        __syncthreads();               // prev tile (or v phase) reads complete
        *(float4*)&stg[0][srow][scol] = rg;
        if (tt < 7)
            rg = *(const float4*)(Sb + sbase + (size_t)((tt + 1) * 16 + srow) * DVH + scol);
        __syncthreads();               // tile staged
        #pragma unroll
        for (int q = 0; q < 16; q++) {
            int kk = tt * 16 + q;
            float4 s4 = *(const float4*)&stg[0][q][c4];
            float a0 = rt[t0][kk], a1 = rt[t0 + 1][kk];
            acc[0][0] += a0 * s4.x; acc[0][1] += a0 * s4.y;
            acc[0][2] += a0 * s4.z; acc[0][3] += a0 * s4.w;
            acc[1][0] += a1 * s4.x; acc[1][1] += a1 * s4.y;
            acc[1][2] += a1 * s4.z; acc[1][3] += a1 * s4.w;
        }
    }
    // groupnorm + affine + silu(g) gate, y f32 in place over v
    int cbase = h * DVH + c4;
    float4 gwA = *(const float4*)(gnw + cbase);
    float4 gbA = *(const float4*)(gnb + cbase);
    float gwv[4] = {gwA.x, gwA.y, gwA.z, gwA.w};
    float gbv[4] = {gbA.x, gbA.y, gbA.z, gbA.w};
    #pragma unroll
    for (int i = 0; i < 2; i++) {
        float sum = 0.f, sq = 0.f;
        #pragma unroll
        for (int jj = 0; jj < 4; jj++) {
            sum += acc[i][jj];
            sq  += acc[i][jj] * acc[i][jj];
        }
        #pragma unroll
        for (int m = 1; m < 64; m <<= 1) {
            sum += __shfl_xor(sum, m);
            sq  += __shfl_xor(sq, m);
        }
        float mean = sum * (1.f / DVH);
        float var = sq * (1.f / DVH) - mean * mean;
        float inv = rsqrtf(var + 1e-5f);
        size_t mrow = (size_t)(tok0 + t0 + i) * VDIM + cbase;
        float4 gA = *(const float4*)(gb_ + mrow);
        float gv[4] = {gA.x, gA.y, gA.z, gA.w};
        float o4[4];
        #pragma unroll
        for (int jj = 0; jj < 4; jj++) {
            float gg = gv[jj];
            float sig = 1.f / (1.f + __expf(-gg));
            o4[jj] = ((acc[i][jj] - mean) * inv * gwv[jj] + gbv[jj]) * (gg * sig);
        }
        *(float4*)(vb + mrow) = make_float4(o4[0], o4[1], o4[2], o4[3]);
    }
}

// ---------------------------------------------------------------------------
// Kernel 6: output GEMM, split precision. 64x128 tile. B-side staged via
// global_load_lds width=16 into LINEAR LDS [128][32] (512 chunks: each wave
// stages 2x64 chunks per buffer); A reg-staged (f2u hi/lo) into 40-pad LDS.
// ---------------------------------------------------------------------------
__global__ __launch_bounds__(256) void k_gemm_out(
    const float* __restrict__ A, const bf16* __restrict__ Bh,
    const bf16* __restrict__ Bl, float* __restrict__ C, int M, int N, int K)
{
    __shared__ unsigned short Ah[64 * 40];
    __shared__ unsigned short Al[64 * 40];
    __shared__ unsigned short Bhs[128 * 32];
    __shared__ unsigned short Bls[128 * 32];
    int tid = threadIdx.x;
    int bm = blockIdx.x * 64, bn = blockIdx.y * 128;
    int lane = tid & 63, w = tid >> 6;
    int wr = w >> 1, wc = w & 1;
    const unsigned short* Bh16 = (const unsigned short*)Bh;
    const unsigned short* Bl16 = (const unsigned short*)Bl;
    f32x4 acc[2][4];
    #pragma unroll
    for (int i = 0; i < 2; i++)
        #pragma unroll
        for (int j = 0; j < 4; j++)
            acc[i][j] = (f32x4){0.f, 0.f, 0.f, 0.f};
    int arow = tid >> 2, acol = (tid & 3) * 8;     // A: 64x32 f32, 8 per thread
    int fr = lane & 15, kb = (lane >> 4) * 8;
    int c0w = w * 128;
    for (int k0 = 0; k0 < K; k0 += 32) {
        float4 t4a = *(const float4*)(A + (size_t)(bm + arow) * K + k0 + acol);
        float4 t4b = *(const float4*)(A + (size_t)(bm + arow) * K + k0 + acol + 4);
        __syncthreads();                   // prev iteration frag reads complete
        #pragma unroll
        for (int q = 0; q < 2; q++) {
            int cb = c0w + q * 64;         // wave-uniform
            int c = cb + lane;
            int row = c >> 2, co = (c & 3) * 8;
            const unsigned short* gh2 = Bh16 + (size_t)(bn + row) * K + k0 + co;
            const unsigned short* gl2 = Bl16 + (size_t)(bn + row) * K + k0 + co;
            __builtin_amdgcn_global_load_lds(
                (const __attribute__((address_space(1))) void*)gh2,
                (__attribute__((address_space(3))) void*)(Bhs + cb * 8), 16, 0, 0);
            __builtin_amdgcn_global_load_lds(
                (const __attribute__((address_space(1))) void*)gl2,
                (__attribute__((address_space(3))) void*)(Bls + cb * 8), 16, 0, 0);
        }
        float av[8] = {t4a.x, t4a.y, t4a.z, t4a.w, t4b.x, t4b.y, t4b.z, t4b.w};
        alignas(16) unsigned short th[8], tl[8];
        #pragma unroll
        for (int q = 0; q < 8; q++) {
            unsigned short hu = f2u(av[q]);
            th[q] = hu;
            tl[q] = f2u(av[q] - u2f(hu));
        }
        *(uint4*)(Ah + arow * 40 + acol) = *(const uint4*)&th[0];
        *(uint4*)(Al + arow * 40 + acol) = *(const uint4*)&tl[0];
        __syncthreads();                   // gload_lds + A writes complete
        bf16x8 afh[2], afl[2], bfh[4], bfl[4];
        #pragma unroll
        for (int i = 0; i < 2; i++) {
            afh[i] = *(const bf16x8*)(Ah + (wr * 32 + i * 16 + fr) * 40 + kb);
            afl[i] = *(const bf16x8*)(Al + (wr * 32 + i * 16 + fr) * 40 + kb);
        }
        #pragma unroll
        for (int j = 0; j < 4; j++) {
            bfh[j] = *(const bf16x8*)(Bhs + (wc * 64 + j * 16 + fr) * 32 + kb);
            bfl[j] = *(const bf16x8*)(Bls + (wc * 64 + j * 16 + fr) * 32 + kb);
        }
        #pragma unroll
        for (int i = 0; i < 2; i++)
            #pragma unroll
            for (int j = 0; j < 4; j++) {
                acc[i][j] = __builtin_amdgcn_mfma_f32_16x16x32_bf16(afh[i], bfh[j], acc[i][j], 0, 0, 0);
                acc[i][j] = __builtin_amdgcn_mfma_f32_16x16x32_bf16(afl[i], bfh[j], acc[i][j], 0, 0, 0);
                acc[i][j] = __builtin_amdgcn_mfma_f32_16x16x32_bf16(afh[i], bfl[j], acc[i][j], 0, 0, 0);
            }
    }
    int er = (lane >> 4) * 4, ec = lane & 15;
    #pragma unroll
    for (int i = 0; i < 2; i++) {
        int gr = bm + wr * 32 + i * 16 + er;
        #pragma unroll
        for (int j = 0; j < 4; j++) {
            int gc = bn + wc * 64 + j * 16 + ec;
            #pragma unroll
            for (int q = 0; q < 4; q++)
                C[(size_t)(gr + q) * N + gc] = acc[i][j][q];
        }
    }
}

// ---------------------------------------------------------------------------
extern "C" void kernel_launch(void* const* d_in, const int* in_sizes, int n_in,
                              void* d_out, int out_size, void* d_ws, size_t ws_size,
                              hipStream_t stream)
{
    const float* h        = (const float*)d_in[0];
    const float* x_mu     = (const float*)d_in[1];
    const float* xl_w1    = (const float*)d_in[2];
    const float* xl_w2    = (const float*)d_in[3];
    const float* xl_b2    = (const float*)d_in[4];
    const float* x_out_w  = (const float*)d_in[5];
    const float* x_bias   = (const float*)d_in[6];
    const float* r_w      = (const float*)d_in[7];
    const float* w_w1     = (const float*)d_in[8];
    const float* w_w2     = (const float*)d_in[9];
    const float* w_b      = (const float*)d_in[10];
    const float* k_w      = (const float*)d_in[11];
    const float* v_w      = (const float*)d_in[12];
    const float* g_w      = (const float*)d_in[13];
    const float* bonus    = (const float*)d_in[14];
    const float* gn_w     = (const float*)d_in[15];
    const float* gn_b     = (const float*)d_in[16];
    const float* o_w      = (const float*)d_in[17];
    float* out = (float*)d_out;

    // Workspace overlay: total 35,733,504 floats = 142.9 MB (proven size)
    float* ws = (float*)d_ws;
    bf16*  wbf  = (bf16*)ws;                       // 8,388,608 bf16 = 4,194,304 slots
    float* rbuf = ws + 4194304;                    // 2,097,152
    float* vbuf = ws + 6291456;                    // 4,194,304 (y f32 in place later)
    float* gbuf = ws + 10485760;                   // 4,194,304
    float* kbuf = ws + 14680064;                   // 2,097,152
    float* ebuf = ws + 16777216;                   // 2,097,152
    float* ubuf = ws + 18874368;                   // 16,384
    float* Dbuf = ws + 18890752;                   // 65,536
    float* BIG  = ws + 18956288;                   // 16,777,216 (X phase / Mbuf)

    // weight hi/lo (bf16 element offsets within wbf)
    bf16* rwb_h = wbf;                  // 524,288
    bf16* kwb_h = wbf + 524288;
    bf16* vwb_h = wbf + 1048576;        // 1,048,576
    bf16* gwb_h = wbf + 2097152;
    bf16* owb_h = wbf + 3145728;
    bf16* rwb_l = wbf + 4194304;
    bf16* kwb_l = wbf + 4718592;
    bf16* vwb_l = wbf + 5242880;
    bf16* gwb_l = wbf + 6291456;
    bf16* owb_l = wbf + 7340032;

    // X phase inside BIG (each bf16 X = 2,097,152 float slots)
    float* Xw = BIG;                           // f32 [0 .. 4,194,304)
    bf16*  Xr = (bf16*)(BIG + 4194304);
    bf16*  Xk = (bf16*)(BIG + 6291456);
    bf16*  Xv = (bf16*)(BIG + 8388608);
    bf16*  Xg = (bf16*)(BIG + 10485760);
    float* x1   = BIG + 12582912;              // 655,360  (dead after mix)
    float* t0bf = BIG + 13238272;              // 131,072  (dead after k_x1b)
    float* w1p  = BIG + 12582912;              // 2,097,152 (after x1/t0 dead; dead before Mbuf)
    float* Mbuf = BIG;                         // full 16,777,216 after X dead
    float* ybuf = vbuf;                        // y f32 in place over v

    // weight conversion MERGED with x1 MFMA phase-1 (independent work)
    k_pre<<<64 + 2048, 256, 0, stream>>>(h, x_mu, xl_w1, t0bf,
                                         r_w, k_w, v_w, g_w, o_w,
                                         rwb_h, rwb_l, kwb_h, kwb_l,
                                         vwb_h, vwb_l, gwb_h, gwb_l,
                                         owb_h, owb_l);
    k_x1b<<<NTOK / 64, 256, 0, stream>>>(t0bf, xl_w2, xl_b2, x1);

    // mix: mixw + mix4 merged (x-parity interleave)
    k_mix<<<dim3(2 * (NTOK / 64), HH / 64), 256, 0, stream>>>(
        h, x1, x_out_w, x_bias, Xw, Xr, Xk, Xv, Xg);

    // projections: four hi/lo MFMA GEMMs (z 0..3) + split-K f32 w1 (z 4..5)
    k_gemm5<<<dim3(NTOK / 128, VDIM / 128, 6), 256, 0, stream>>>(
        Xr, rwb_h, rwb_l, rbuf,
        Xk, kwb_h, kwb_l, kbuf,
        Xv, vwb_h, vwb_l, vbuf,
        Xg, gwb_h, gwb_l, gbuf, NTOK, HH,
        Xw, w_w1, w1p);
    k_we<<<dim3(NTOK / 64, KDIM / 64), 256, 0, stream>>>(w1p, w_w2, w_b, ebuf);

    k_chunkA1<<<dim3(BB * NHD, NCK), 256, 0, stream>>>(ebuf, rbuf, kbuf, vbuf,
                                                       bonus, ubuf, Mbuf, Dbuf);
    k_chunkB<<<dim3(BB * NHD, NCK), 256, 0, stream>>>(Mbuf, Dbuf);
    k_chunkCG<<<dim3(BB * NHD, NCK), 1024, 0, stream>>>(rbuf, kbuf, vbuf, ubuf, Mbuf,
                                                        gbuf, gn_w, gn_b);

    k_gemm_out<<<dim3(NTOK / 64, HH / 128), 256, 0, stream>>>(ybuf, owb_h, owb_l, out, NTOK, HH, VDIM);
}

// Round 23
// 290.709 us; speedup vs baseline: 1.0431x; 1.0431x over previous
//
#include <hip/hip_runtime.h>
#include <hip/hip_bf16.h>
#include <math.h>

// Problem constants
static constexpr int BB = 4;
static constexpr int TT = 1024;
static constexpr int HH = 1024;
static constexpr int NHD = 4;
static constexpr int KDIM = 512;
static constexpr int VDIM = 1024;
static constexpr int DKH = 128;   // KD / NH
static constexpr int DVH = 256;   // VD / NH
static constexpr int RR = 32;
static constexpr int R5D = 160;
static constexpr int GG = 64;
static constexpr int NTOK = BB * TT;   // 4096
static constexpr int CK = 32;          // chunk length
static constexpr int NCK = TT / CK;    // 32 chunks per sequence
static constexpr int WKS = 8;          // split-K factor for the w1 gemm

typedef __bf16 bf16x8 __attribute__((ext_vector_type(8)));
typedef float f32x4 __attribute__((ext_vector_type(4)));
typedef __hip_bfloat16 bf16;

static __device__ inline unsigned short f2u(float v) {
    __hip_bfloat16 b = __float2bfloat16(v);
    unsigned short u; __builtin_memcpy(&u, &b, 2); return u;
}
static __device__ inline float u2f(unsigned short u) {
    __hip_bfloat16 b; __builtin_memcpy(&b, &u, 2); return __bfloat162float(b);
}

// ---------------------------------------------------------------------------
// Kernel 0: f32 -> bf16 hi/lo pairs, all 5 weights in one launch
// ---------------------------------------------------------------------------
__global__ __launch_bounds__(256) void k_f2b2_all(
    const float* __restrict__ r_w, const float* __restrict__ k_w,
    const float* __restrict__ v_w, const float* __restrict__ g_w,
    const float* __restrict__ o_w,
    bf16* __restrict__ rh, bf16* __restrict__ rl,
    bf16* __restrict__ kh, bf16* __restrict__ kl,
    bf16* __restrict__ vh, bf16* __restrict__ vl,
    bf16* __restrict__ gh, bf16* __restrict__ gl,
    bf16* __restrict__ oh, bf16* __restrict__ ol)
{
    size_t g = ((size_t)blockIdx.x * 256 + threadIdx.x) * 8;
    const float* s; bf16 *hi, *lo; size_t off;
    if (g < 524288)       { s = r_w; hi = rh; lo = rl; off = g; }
    else if (g < 1048576) { s = k_w; hi = kh; lo = kl; off = g - 524288; }
    else if (g < 2097152) { s = v_w; hi = vh; lo = vl; off = g - 1048576; }
    else if (g < 3145728) { s = g_w; hi = gh; lo = gl; off = g - 2097152; }
    else                  { s = o_w; hi = oh; lo = ol; off = g - 3145728; }
    #pragma unroll
    for (int j = 0; j < 8; j++) {
        float v = s[off + j];
        bf16 hb = __float2bfloat16(v);
        hi[off + j] = hb;
        lo[off + j] = __float2bfloat16(v - __bfloat162float(hb));
    }
}

// ---------------------------------------------------------------------------
// Kernel 1a (k_x1mm): t0[4096x32] = tanh( x_lerp @ w1^T ) via bf16 MFMA.
// ---------------------------------------------------------------------------
__global__ __launch_bounds__(256) void k_x1mm(
    const float* __restrict__ h, const float* __restrict__ mu,
    const float* __restrict__ w1, float* __restrict__ t0)
{
    __shared__ unsigned short Al[64][40];
    __shared__ unsigned short Bl[32][40];
    int tid = threadIdx.x;
    int m0 = blockIdx.x * 64;
    int lane = tid & 63, w = tid >> 6;
    f32x4 acc[2];
    acc[0] = (f32x4){0.f, 0.f, 0.f, 0.f};
    acc[1] = (f32x4){0.f, 0.f, 0.f, 0.f};
    int ar = tid >> 2, ac0 = (tid & 3) * 8;        // A stage: 64x32, 8 per thread
    int br = tid >> 3, bc0 = (tid & 7) * 4;        // B stage: 32x32, 4 per thread
    int fr = lane & 15, kb = lane >> 4;
    int mrow = m0 + ar;
    int trow = mrow & (TT - 1);
    const float* hp = h + (size_t)mrow * HH;
    for (int k0 = 0; k0 < HH; k0 += 32) {
        float av[8];
        #pragma unroll
        for (int j = 0; j < 8; j += 4) {
            float4 c4 = *(const float4*)(hp + k0 + ac0 + j);
            float4 p4 = make_float4(0.f, 0.f, 0.f, 0.f);
            if (trow > 0) p4 = *(const float4*)(hp + k0 + ac0 + j - HH);
            float4 m4 = *(const float4*)(mu + k0 + ac0 + j);
            av[j + 0] = c4.x + (p4.x - c4.x) * m4.x;
            av[j + 1] = c4.y + (p4.y - c4.y) * m4.y;
            av[j + 2] = c4.z + (p4.z - c4.z) * m4.z;
            av[j + 3] = c4.w + (p4.w - c4.w) * m4.w;
        }
        float4 b4 = *(const float4*)(w1 + (size_t)br * HH + k0 + bc0);
        __syncthreads();
        #pragma unroll
        for (int j = 0; j < 8; j++) Al[ar][ac0 + j] = f2u(av[j]);
        Bl[br][bc0 + 0] = f2u(b4.x); Bl[br][bc0 + 1] = f2u(b4.y);
        Bl[br][bc0 + 2] = f2u(b4.z); Bl[br][bc0 + 3] = f2u(b4.w);
        __syncthreads();
        bf16x8 af = *(const bf16x8*)(&Al[w * 16 + fr][kb * 8]);
        bf16x8 bf0 = *(const bf16x8*)(&Bl[fr][kb * 8]);
        bf16x8 bf1 = *(const bf16x8*)(&Bl[16 + fr][kb * 8]);
        acc[0] = __builtin_amdgcn_mfma_f32_16x16x32_bf16(af, bf0, acc[0], 0, 0, 0);
        acc[1] = __builtin_amdgcn_mfma_f32_16x16x32_bf16(af, bf1, acc[1], 0, 0, 0);
    }
    int er = (lane >> 4) * 4, ec = lane & 15;
    #pragma unroll
    for (int j = 0; j < 2; j++) {
        #pragma unroll
        for (int q = 0; q < 4; q++) {
            int gr = m0 + w * 16 + er + q;
            t0[(size_t)gr * RR + j * 16 + ec] = tanhf(acc[j][q]);
        }
    }
}

// ---------------------------------------------------------------------------
// Kernel 1b (k_x1b): x1[4096x160] = tanh( t0 @ w2^T + b2 ).  K=32.
// ---------------------------------------------------------------------------
__global__ __launch_bounds__(256) void k_x1b(
    const float* __restrict__ t0, const float* __restrict__ w2,
    const float* __restrict__ b2, float* __restrict__ x1out)
{
    __shared__ float t0s[64][33];
    __shared__ float w2s[R5D * RR];
    __shared__ float b2s[R5D];
    int tid = threadIdx.x;
    int m0 = blockIdx.x * 64;
    {
        int row = tid >> 2, c0 = (tid & 3) * 8;
        float4 a = *(const float4*)(t0 + (size_t)(m0 + row) * RR + c0);
        float4 b = *(const float4*)(t0 + (size_t)(m0 + row) * RR + c0 + 4);
        t0s[row][c0 + 0] = a.x; t0s[row][c0 + 1] = a.y;
        t0s[row][c0 + 2] = a.z; t0s[row][c0 + 3] = a.w;
        t0s[row][c0 + 4] = b.x; t0s[row][c0 + 5] = b.y;
        t0s[row][c0 + 6] = b.z; t0s[row][c0 + 7] = b.w;
    }
    for (int i = tid; i < R5D * RR; i += 256) w2s[i] = w2[i];
    if (tid < R5D) b2s[tid] = b2[tid];
    __syncthreads();
    int tt = tid & 63, cg = tid >> 6;
    float t0r[32];
    #pragma unroll
    for (int q = 0; q < 32; q++) t0r[q] = t0s[tt][q];
    float* xo = x1out + (size_t)(m0 + tt) * R5D + cg * 40;
    for (int c = 0; c < 40; c++) {
        const float* wr = w2s + (cg * 40 + c) * RR;
        float s = b2s[cg * 40 + c];
        #pragma unroll
        for (int q = 0; q < 32; q++) s += t0r[q] * wr[q];
        xo[c] = tanhf(s);
    }
}

// ---------------------------------------------------------------------------
// Kernel 2a (k_mixw): n=1 slice only (w path, f32 exact).
// ---------------------------------------------------------------------------
__global__ __launch_bounds__(256) void k_mixw(
    const float* __restrict__ h, const float* __restrict__ x1,
    const float* __restrict__ xow, const float* __restrict__ xb,
    float* __restrict__ xw)
{
    int m0 = blockIdx.x * 64;
    int h0 = blockIdx.y * 64;
    int tid = threadIdx.x;
    __shared__ float x1sT[32][68];
    __shared__ float xosT[32][68];
    int rr = tid & 63, cg = tid >> 6;    // cg = wave id, 8 cols each
    {
        const float* xp = x1 + (size_t)(m0 + rr) * R5D + 32 + cg * 8;
        const float* wp = xow + (size_t)(h0 + rr) * R5D + 32 + cg * 8;
        float4 a0 = *(const float4*)xp, a1 = *(const float4*)(xp + 4);
        float4 b0 = *(const float4*)wp, b1 = *(const float4*)(wp + 4);
        x1sT[cg * 8 + 0][rr] = a0.x; x1sT[cg * 8 + 1][rr] = a0.y;
        x1sT[cg * 8 + 2][rr] = a0.z; x1sT[cg * 8 + 3][rr] = a0.w;
        x1sT[cg * 8 + 4][rr] = a1.x; x1sT[cg * 8 + 5][rr] = a1.y;
        x1sT[cg * 8 + 6][rr] = a1.z; x1sT[cg * 8 + 7][rr] = a1.w;
        xosT[cg * 8 + 0][rr] = b0.x; xosT[cg * 8 + 1][rr] = b0.y;
        xosT[cg * 8 + 2][rr] = b0.z; xosT[cg * 8 + 3][rr] = b0.w;
        xosT[cg * 8 + 4][rr] = b1.x; xosT[cg * 8 + 5][rr] = b1.y;
        xosT[cg * 8 + 6][rr] = b1.z; xosT[cg * 8 + 7][rr] = b1.w;
    }
    int tx = tid & 15, ty = tid >> 4;
    float creg[4][4], dreg[4][4];
    #pragma unroll
    for (int i = 0; i < 4; i++) {
        int m = m0 + ty * 4 + i;
        int t = m & (TT - 1);
        const float* hp = h + (size_t)m * HH + h0 + tx * 4;
        float4 c4 = *(const float4*)hp;
        float4 p4 = make_float4(0.f, 0.f, 0.f, 0.f);
        if (t > 0) p4 = *(const float4*)(hp - HH);
        creg[i][0] = c4.x; dreg[i][0] = p4.x - c4.x;
        creg[i][1] = c4.y; dreg[i][1] = p4.y - c4.y;
        creg[i][2] = c4.z; dreg[i][2] = p4.z - c4.z;
        creg[i][3] = c4.w; dreg[i][3] = p4.w - c4.w;
    }
    __syncthreads();
    float acc[4][4] = {};
    #pragma unroll
    for (int r2 = 0; r2 < 32; r2++) {
        float4 a4 = *(const float4*)&x1sT[r2][ty * 4];
        float4 b4 = *(const float4*)&xosT[r2][tx * 4];
        float aa[4] = {a4.x, a4.y, a4.z, a4.w};
        float bb[4] = {b4.x, b4.y, b4.z, b4.w};
        #pragma unroll
        for (int i = 0; i < 4; i++)
            #pragma unroll
            for (int j = 0; j < 4; j++)
                acc[i][j] += aa[i] * bb[j];
    }
    float4 xb4 = *(const float4*)(xb + HH + h0 + tx * 4);   // n=1 row of x_bias
    float xbv[4] = {xb4.x, xb4.y, xb4.z, xb4.w};
    #pragma unroll
    for (int i = 0; i < 4; i++) {
        size_t idx = (size_t)(m0 + ty * 4 + i) * HH + h0 + tx * 4;
        float v[4];
        #pragma unroll
        for (int j = 0; j < 4; j++)
            v[j] = creg[i][j] + dreg[i][j] * (acc[i][j] + xbv[j]);
        *(float4*)(xw + idx) = make_float4(v[0], v[1], v[2], v[3]);
    }
}

// ---------------------------------------------------------------------------
// Kernel 2b (k_mix4): n in {0,2,3,4} via direct-from-global MFMA fragments.
// ---------------------------------------------------------------------------
__global__ __launch_bounds__(256) void k_mix4(
    const float* __restrict__ h, const float* __restrict__ x1,
    const float* __restrict__ xow, const float* __restrict__ xb,
    bf16* __restrict__ xr, bf16* __restrict__ xk,
    bf16* __restrict__ xv, bf16* __restrict__ xg)
{
    int m0 = blockIdx.x * 64;
    int h0 = blockIdx.y * 64;
    int tid = threadIdx.x;
    int lane = tid & 63, w = tid >> 6;
    int fr = lane & 15, kb = (lane >> 4) * 8;
    int er = (lane >> 4) * 4, ec = lane & 15;
    float creg[4][4], dreg[4][4];
    #pragma unroll
    for (int q = 0; q < 4; q++) {
        int m = m0 + w * 16 + er + q;
        int t = m & (TT - 1);
        const float* hp = h + (size_t)m * HH;
        #pragma unroll
        for (int j = 0; j < 4; j++) {
            int hh = h0 + j * 16 + ec;
            float c = hp[hh];
            float p = (t > 0) ? hp[hh - HH] : 0.f;
            creg[q][j] = c;
            dreg[q][j] = p - c;
        }
    }
    bf16* outs[4] = {xr, xk, xv, xg};
    const int ns[4] = {0, 2, 3, 4};
    #pragma unroll
    for (int ni = 0; ni < 4; ni++) {
        int n = ns[ni];
        const float* ap = x1 + (size_t)(m0 + w * 16 + fr) * R5D + n * 32 + kb;
        float4 a0 = *(const float4*)ap;
        float4 a1 = *(const float4*)(ap + 4);
        alignas(16) unsigned short ta[8];
        ta[0] = f2u(a0.x); ta[1] = f2u(a0.y); ta[2] = f2u(a0.z); ta[3] = f2u(a0.w);
        ta[4] = f2u(a1.x); ta[5] = f2u(a1.y); ta[6] = f2u(a1.z); ta[7] = f2u(a1.w);
        bf16x8 af = *(const bf16x8*)ta;
        f32x4 accj[4];
        #pragma unroll
        for (int j = 0; j < 4; j++) {
            const float* bp = xow + (size_t)(h0 + j * 16 + fr) * R5D + n * 32 + kb;
            float4 b0 = *(const float4*)bp;
            float4 b1 = *(const float4*)(bp + 4);
            alignas(16) unsigned short tb[8];
            tb[0] = f2u(b0.x); tb[1] = f2u(b0.y); tb[2] = f2u(b0.z); tb[3] = f2u(b0.w);
            tb[4] = f2u(b1.x); tb[5] = f2u(b1.y); tb[6] = f2u(b1.z); tb[7] = f2u(b1.w);
            bf16x8 bf_ = *(const bf16x8*)tb;
            f32x4 z = (f32x4){0.f, 0.f, 0.f, 0.f};
            accj[j] = __builtin_amdgcn_mfma_f32_16x16x32_bf16(af, bf_, z, 0, 0, 0);
        }
        bf16* op = outs[ni];
        #pragma unroll
        for (int j = 0; j < 4; j++) {
            float xbv = xb[n * HH + h0 + j * 16 + ec];
            #pragma unroll
            for (int q = 0; q < 4; q++) {
                float val = creg[q][j] + dreg[q][j] * (accj[j][q] + xbv);
                op[(size_t)(m0 + w * 16 + er + q) * HH + h0 + j * 16 + ec] =
                    __float2bfloat16(val);
            }
        }
    }
}

// ---------------------------------------------------------------------------
// Kernel 3a (k_gemm_hl4): FOUR hi/lo GEMMs in one launch (z: 0=r,1=k N=512;
// 2=v,3=g N=1024). 128x128 tile. Staging via global_load_lds width=16 into
// LINEAR LDS [128][32] (wave-uniform dest + lane*16B). m97-proven structure.
// ---------------------------------------------------------------------------
__global__ __launch_bounds__(256) void k_gemm_hl4(
    const bf16* __restrict__ A0, const bf16* __restrict__ Bh0,
    const bf16* __restrict__ Bl0, float* __restrict__ C0,
    const bf16* __restrict__ A1, const bf16* __restrict__ Bh1,
    const bf16* __restrict__ Bl1, float* __restrict__ C1,
    const bf16* __restrict__ A2, const bf16* __restrict__ Bh2,
    const bf16* __restrict__ Bl2, float* __restrict__ C2,
    const bf16* __restrict__ A3, const bf16* __restrict__ Bh3,
    const bf16* __restrict__ Bl3, float* __restrict__ C3,
    int M, int K)
{
    int z = blockIdx.z;
    const bf16* A;
    const bf16* Bh;
    const bf16* Bl;
    float* C;
    int N;
    if (z == 0)      { A = A0; Bh = Bh0; Bl = Bl0; C = C0; N = KDIM; }
    else if (z == 1) { A = A1; Bh = Bh1; Bl = Bl1; C = C1; N = KDIM; }
    else if (z == 2) { A = A2; Bh = Bh2; Bl = Bl2; C = C2; N = VDIM; }
    else             { A = A3; Bh = Bh3; Bl = Bl3; C = C3; N = VDIM; }
    int bn = blockIdx.y * 128;
    if (bn >= N) return;
    __shared__ unsigned short As[128 * 32];
    __shared__ unsigned short Bhs[128 * 32];
    __shared__ unsigned short Bls[128 * 32];
    int tid = threadIdx.x;
    int bm = blockIdx.x * 128;
    int lane = tid & 63, w = tid >> 6;
    int wr = w >> 1, wc = w & 1;
    const unsigned short* A16 = (const unsigned short*)A;
    const unsigned short* Bh16 = (const unsigned short*)Bh;
    const unsigned short* Bl16 = (const unsigned short*)Bl;
    f32x4 acc[4][4];
    #pragma unroll
    for (int i = 0; i < 4; i++)
        #pragma unroll
        for (int j = 0; j < 4; j++)
            acc[i][j] = (f32x4){0.f, 0.f, 0.f, 0.f};
    int fr = lane & 15, kb = (lane >> 4) * 8;
    // chunk mapping: chunk c (16B) covers row c>>2, col (c&3)*8 shorts.
    int c0w = w * 128;
    for (int k0 = 0; k0 < K; k0 += 32) {
        #pragma unroll
        for (int q = 0; q < 2; q++) {
            int cb = c0w + q * 64;            // wave-uniform
            int c = cb + lane;
            int row = c >> 2, co = (c & 3) * 8;
            const unsigned short* ga = A16 + (size_t)(bm + row) * K + k0 + co;
            const unsigned short* gh2 = Bh16 + (size_t)(bn + row) * K + k0 + co;
            const unsigned short* gl2 = Bl16 + (size_t)(bn + row) * K + k0 + co;
            __builtin_amdgcn_global_load_lds(
                (const __attribute__((address_space(1))) void*)ga,
                (__attribute__((address_space(3))) void*)(As + cb * 8), 16, 0, 0);
            __builtin_amdgcn_global_load_lds(
                (const __attribute__((address_space(1))) void*)gh2,
                (__attribute__((address_space(3))) void*)(Bhs + cb * 8), 16, 0, 0);
            __builtin_amdgcn_global_load_lds(
                (const __attribute__((address_space(1))) void*)gl2,
                (__attribute__((address_space(3))) void*)(Bls + cb * 8), 16, 0, 0);
        }
        __syncthreads();
        bf16x8 af[4], bfh[4], bfl[4];
        #pragma unroll
        for (int i = 0; i < 4; i++) {
            af[i]  = *(const bf16x8*)(As + (wr * 64 + i * 16 + fr) * 32 + kb);
            bfh[i] = *(const bf16x8*)(Bhs + (wc * 64 + i * 16 + fr) * 32 + kb);
            bfl[i] = *(const bf16x8*)(Bls + (wc * 64 + i * 16 + fr) * 32 + kb);
        }
        #pragma unroll
        for (int i = 0; i < 4; i++)
            #pragma unroll
            for (int j = 0; j < 4; j++) {
                acc[i][j] = __builtin_amdgcn_mfma_f32_16x16x32_bf16(af[i], bfh[j], acc[i][j], 0, 0, 0);
                acc[i][j] = __builtin_amdgcn_mfma_f32_16x16x32_bf16(af[i], bfl[j], acc[i][j], 0, 0, 0);
            }
        __syncthreads();
    }
    int er = (lane >> 4) * 4, ec = lane & 15;
    #pragma unroll
    for (int i = 0; i < 4; i++) {
        int gr = bm + wr * 64 + i * 16 + er;
        #pragma unroll
        for (int j = 0; j < 4; j++) {
            int gc = bn + wc * 64 + j * 16 + ec;
            #pragma unroll
            for (int q = 0; q < 4; q++)
                C[(size_t)(gr + q) * N + gc] = acc[i][j][q];
        }
    }
}

// ---------------------------------------------------------------------------
// Kernel 3b (k_w1): split-K partial GEMM for the w path.
// ---------------------------------------------------------------------------
__global__ __launch_bounds__(256) void k_w1(
    const float* __restrict__ A, const float* __restrict__ Bm,
    float* __restrict__ P)
{
    __shared__ float As[16][68];
    __shared__ float Bs[16][68];
    int tid = threadIdx.x;
    int bm = blockIdx.x * 64;
    int ks = blockIdx.y;
    int kbase = ks * (HH / WKS);       // 128-wide K slice
    int tx = tid & 15, ty = tid >> 4;
    int lr = tid >> 2;
    int lk = (tid & 3) * 4;
    float acc[4][4] = {};
    for (int k0 = 0; k0 < HH / WKS; k0 += 16) {
        float4 av = *(const float4*)(A + (size_t)(bm + lr) * HH + kbase + k0 + lk);
        float4 bv = *(const float4*)(Bm + (size_t)lr * HH + kbase + k0 + lk);
        As[lk + 0][lr] = av.x; As[lk + 1][lr] = av.y;
        As[lk + 2][lr] = av.z; As[lk + 3][lr] = av.w;
        Bs[lk + 0][lr] = bv.x; Bs[lk + 1][lr] = bv.y;
        Bs[lk + 2][lr] = bv.z; Bs[lk + 3][lr] = bv.w;
        __syncthreads();
        #pragma unroll
        for (int kk = 0; kk < 16; kk++) {
            float4 a4 = *(const float4*)&As[kk][ty * 4];
            float4 b4 = *(const float4*)&Bs[kk][tx * 4];
            float aa[4] = {a4.x, a4.y, a4.z, a4.w};
            float bb[4] = {b4.x, b4.y, b4.z, b4.w};
            #pragma unroll
            for (int i = 0; i < 4; i++)
                #pragma unroll
                for (int j = 0; j < 4; j++)
                    acc[i][j] += aa[i] * bb[j];
        }
        __syncthreads();
    }
    #pragma unroll
    for (int i = 0; i < 4; i++) {
        size_t row = (size_t)ks * NTOK + bm + ty * 4 + i;
        *(float4*)(P + row * GG + tx * 4) =
            make_float4(acc[i][0], acc[i][1], acc[i][2], acc[i][3]);
    }
}

// ---------------------------------------------------------------------------
// Kernel 3c (k_we): e = exp( tanh(sum_ks P) @ w_w2^T + w_b ).
// ---------------------------------------------------------------------------
__global__ __launch_bounds__(256) void k_we(
    const float* __restrict__ P, const float* __restrict__ w_w2,
    const float* __restrict__ w_b, float* __restrict__ eb)
{
    __shared__ float As[64][65];
    __shared__ float Bs[64][65];
    int tid = threadIdx.x;
    int bm = blockIdx.x * 64, bn = blockIdx.y * 64;
    {
        int r = tid >> 2, c0 = (tid & 3) * 16;
        float s[16];
        #pragma unroll
        for (int j = 0; j < 16; j++) s[j] = 0.f;
        for (int ks = 0; ks < WKS; ks++) {
            const float* pp = P + ((size_t)ks * NTOK + bm + r) * GG + c0;
            #pragma unroll
            for (int j = 0; j < 16; j += 4) {
                float4 v = *(const float4*)(pp + j);
                s[j + 0] += v.x; s[j + 1] += v.y; s[j + 2] += v.z; s[j + 3] += v.w;
            }
        }
        #pragma unroll
        for (int j = 0; j < 16; j++) As[r][c0 + j] = tanhf(s[j]);
        const float* bp = w_w2 + (size_t)(bn + r) * GG + c0;
        #pragma unroll
        for (int j = 0; j < 16; j += 4) {
            float4 v = *(const float4*)(bp + j);
            Bs[r][c0 + j + 0] = v.x; Bs[r][c0 + j + 1] = v.y;
            Bs[r][c0 + j + 2] = v.z; Bs[r][c0 + j + 3] = v.w;
        }
    }
    __syncthreads();
    int tx = tid & 15, ty = tid >> 4;
    float acc[4][4] = {};
    #pragma unroll 8
    for (int kk = 0; kk < GG; kk++) {
        float aa[4], bb[4];
        #pragma unroll
        for (int i = 0; i < 4; i++) aa[i] = As[ty * 4 + i][kk];
        #pragma unroll
        for (int j = 0; j < 4; j++) bb[j] = Bs[tx * 4 + j][kk];
        #pragma unroll
        for (int i = 0; i < 4; i++)
            #pragma unroll
            for (int j = 0; j < 4; j++)
                acc[i][j] += aa[i] * bb[j];
    }
    float4 wb4 = *(const float4*)(w_b + bn + tx * 4);
    float wbv[4] = {wb4.x, wb4.y, wb4.z, wb4.w};
    #pragma unroll
    for (int i = 0; i < 4; i++) {
        float v[4];
        #pragma unroll
        for (int j = 0; j < 4; j++) v[j] = __expf(acc[i][j] + wbv[j]);
        *(float4*)(eb + (size_t)(bm + ty * 4 + i) * KDIM + bn + tx * 4) =
            make_float4(v[0], v[1], v[2], v[3]);
    }
}

// ---------------------------------------------------------------------------
// Kernel 5a (chunkA1): LDS-staged r/k/e; 2-way-parallel cumsum; r~,k~ in place;
// M = (k~ * Dtot)^T v; Dtot out; u fused.
// ---------------------------------------------------------------------------
__global__ __launch_bounds__(256) void k_chunkA1(
    const float* __restrict__ eb, float* __restrict__ rb,
    float* __restrict__ kb, const float* __restrict__ vb,
    const float* __restrict__ bonus, float* __restrict__ ub,
    float* __restrict__ Mb, float* __restrict__ Db)
{
    int bh = blockIdx.x;       // b*NH + h (h fast)
    int ck = blockIdx.y;       // 0..31
    int h = bh & 3, b = bh >> 2;
    int tok0 = b * TT + ck * CK;
    int tid = threadIdx.x;
    __shared__ float Ls[CK][128];
    __shared__ float rs[CK][129];
    __shared__ float kt[CK][129];
    __shared__ float vsm[CK][68];
    __shared__ float Dts[128];
    __shared__ float up[CK][8];
    #pragma unroll
    for (int i = 0; i < 16; i++) {
        int idx = i * 256 + tid;
        int t = idx >> 7, c = idx & 127;
        size_t g = (size_t)(tok0 + t) * KDIM + h * DKH + c;
        Ls[t][c] = eb[g];
        rs[t][c] = rb[g];
        kt[t][c] = kb[g];
    }
    __syncthreads();
    {
        int c = tid & 127, hf = tid >> 7;
        float run = 0.f;
        if (hf) {
            #pragma unroll
            for (int t = 0; t < 16; t++) run += Ls[t][c];
        }
        __syncthreads();    // prefix reads of Ls done before overwrites below
        float bc = bonus[h * DKH + c];
        #pragma unroll
        for (int tt2 = 0; tt2 < 16; tt2++) {
            int t = hf * 16 + tt2;
            size_t g = (size_t)(tok0 + t) * KDIM + h * DKH + c;
            float e = Ls[t][c];
            float rv = rs[t][c];
            float kv = kt[t][c];
            rb[g] = rv * __expf(-run);
            Ls[t][c] = rv * kv * bc;          // bonus partial
            run += e;
            float ks = kv * __expf(run);
            kt[t][c] = ks;
            kb[g] = ks;
        }
        if (hf) {
            float dt = __expf(-run);
            Dts[c] = dt;
            Db[(size_t)(bh * NCK + ck) * 128 + c] = dt;
        }
    }
    __syncthreads();
    {
        int t = tid >> 3, seg = tid & 7;
        float s = 0.f;
        #pragma unroll
        for (int q = 0; q < 16; q++) s += Ls[t][seg * 16 + q];
        up[t][seg] = s;
    }
    __syncthreads();
    if (tid < CK) {
        float s = 0.f;
        #pragma unroll
        for (int q = 0; q < 8; q++) s += up[tid][q];
        ub[(size_t)(tok0 + tid) * NHD + h] = s;
    }
    for (int jb = 0; jb < 4; jb++) {
        {
            int j = tid & 63, r0 = tid >> 6;
            #pragma unroll
            for (int i = 0; i < 8; i++) {
                int s = r0 + 4 * i;
                vsm[s][j] = vb[(size_t)(tok0 + s) * VDIM + h * DVH + jb * 64 + j];
            }
        }
        __syncthreads();
        {
            int kk0 = (tid >> 3) * 4;
            int j0 = (tid & 7) * 8;
            float m[4][8] = {};
            for (int s = 0; s < CK; s++) {
                float4 kv = *(const float4*)&kt[s][kk0];
                float4 v0 = *(const float4*)&vsm[s][j0];
                float4 v1 = *(const float4*)&vsm[s][j0 + 4];
                float ka[4] = {kv.x, kv.y, kv.z, kv.w};
                float va[8] = {v0.x, v0.y, v0.z, v0.w, v1.x, v1.y, v1.z, v1.w};
                #pragma unroll
                for (int i = 0; i < 4; i++)
                    #pragma unroll
                    for (int jj = 0; jj < 8; jj++)
                        m[i][jj] += ka[i] * va[jj];
            }
            #pragma unroll
            for (int i = 0; i < 4; i++) {
                float d = Dts[kk0 + i];
                size_t mb = ((size_t)(bh * NCK + ck) * 128 + kk0 + i) * DVH + jb * 64 + j0;
                *(float4*)(Mb + mb)     = make_float4(m[i][0] * d, m[i][1] * d, m[i][2] * d, m[i][3] * d);
                *(float4*)(Mb + mb + 4) = make_float4(m[i][4] * d, m[i][5] * d, m[i][6] * d, m[i][7] * d);
            }
        }
        __syncthreads();
    }
}

// ---------------------------------------------------------------------------
// Kernel 5b (chunkB): sequential over chunks with register prefetch.
// Coalesced mapping: thread = (k-row via wave id, float4 of j via lane).
// Consecutive lanes read/write consecutive float4s (1KB/row segment);
// Db load is wave-uniform (scalar). Same per-element recurrence order.
// ---------------------------------------------------------------------------
__global__ __launch_bounds__(256) void k_chunkB(
    float* __restrict__ MS, const float* __restrict__ Db)
{
    int bh = blockIdx.x;
    int ks = blockIdx.y;               // 0..31 -> 4-row k group
    int tid = threadIdx.x;
    int k = ks * 4 + (tid >> 6);       // wave-uniform row
    int j0 = (tid & 63) * 4;           // lane-consecutive float4
    float4 S = make_float4(0.f, 0.f, 0.f, 0.f);
    float4 m; float d;
    {
        size_t kb0 = (size_t)(bh * NCK) * 128 + k;
        m = *(const float4*)(MS + kb0 * DVH + j0);
        d = Db[kb0];
    }
    for (int c = 0; c < NCK; c++) {
        size_t kbc = (size_t)(bh * NCK + c) * 128 + k;
        float4 mc = m; float dc = d;
        if (c + 1 < NCK) {
            size_t kbn = (size_t)(bh * NCK + c + 1) * 128 + k;
            m = *(const float4*)(MS + kbn * DVH + j0);
            d = Db[kbn];
        }
        *(float4*)(MS + kbc * DVH + j0) = S;
        S.x = S.x * dc + mc.x;
        S.y = S.y * dc + mc.y;
        S.z = S.z * dc + mc.z;
        S.w = S.w * dc + mc.w;
    }
}

// ---------------------------------------------------------------------------
// Kernel 5c (chunkCG v3, 1024 threads): P = mask(r~ k~^T, diag=u);
// o = P@v + r~@S (f32 regs); groupnorm; silu(g) gate; y f32 IN PLACE over v.
// S staged through LDS in 16-row tiles (each S byte crosses L2 once).
// ---------------------------------------------------------------------------
__global__ __launch_bounds__(1024) void k_chunkCG(
    const float* __restrict__ rb, const float* __restrict__ kb,
    float* __restrict__ vb, const float* __restrict__ ub,
    const float* __restrict__ Sb, const float* __restrict__ gb_,
    const float* __restrict__ gnw, const float* __restrict__ gnb)
{
    int bh = blockIdx.x, ck = blockIdx.y;
    int h = bh & 3, b = bh >> 2;
    int tok0 = b * TT + ck * CK;
    int tid = threadIdx.x;
    __shared__ float rt[CK][128];
    __shared__ float kt[CK][129];
    __shared__ float Ps[CK][33];
    __shared__ float stg[2][16][260];   // v staging (both halves), then S tiles in stg[0]
    #pragma unroll
    for (int i = 0; i < 4; i++) {
        int idx = i * 1024 + tid;
        int t = idx >> 7, c = idx & 127;
        size_t g = (size_t)(tok0 + t) * KDIM + h * DKH + c;
        rt[t][c] = rb[g];
        kt[t][c] = kb[g];
    }
    // stage v [32][256]
    {
        int r = tid >> 5, c0 = (tid & 31) * 8;
        const float* vp = vb + (size_t)(tok0 + r) * VDIM + h * DVH + c0;
        float4 a = *(const float4*)vp;
        float4 b2 = *(const float4*)(vp + 4);
        *(float4*)&stg[r >> 4][r & 15][c0]     = a;
        *(float4*)&stg[r >> 4][r & 15][c0 + 4] = b2;
    }
    __syncthreads();
    // P: 1 entry per thread
    {
        int t = tid >> 5, s = tid & 31;
        float a0 = 0.f;
        for (int k4 = 0; k4 < 128; k4 += 4) {
            float4 a = *(const float4*)&rt[t][k4];
            float4 b0 = *(const float4*)&kt[s][k4];
            a0 += a.x * b0.x + a.y * b0.y + a.z * b0.z + a.w * b0.w;
        }
        float u0 = ub[(size_t)(tok0 + t) * NHD + h];
        Ps[t][s] = (s < t) ? a0 : (s == t ? u0 : 0.f);
    }
    __syncthreads();
    int t0 = (tid >> 6) * 2;           // wave owns tokens t0, t0+1
    int c4 = (tid & 63) * 4;           // 64 lanes x 4 cols = full 256-col row
    float acc[2][4] = {};
    // intra-chunk: P @ v (from LDS)
    for (int s = 0; s < CK; s++) {
        float4 v0 = *(const float4*)&stg[s >> 4][s & 15][c4];
        float p0 = Ps[t0][s], p1 = Ps[t0 + 1][s];
        acc[0][0] += p0 * v0.x; acc[0][1] += p0 * v0.y;
        acc[0][2] += p0 * v0.z; acc[0][3] += p0 * v0.w;
        acc[1][0] += p1 * v0.x; acc[1][1] += p1 * v0.y;
        acc[1][2] += p1 * v0.z; acc[1][3] += p1 * v0.w;
    }
    // inter-chunk: r~ @ S, S tiled through LDS (each S byte read once from L2)
    size_t sbase = (size_t)(bh * NCK + ck) * 128 * DVH;
    int srow = tid >> 6;               // 0..15
    int scol = (tid & 63) * 4;
    float4 rg = *(const float4*)(Sb + sbase + (size_t)srow * DVH + scol);
    for (int tt = 0; tt < 8; tt++) {
        __syncthreads();               // prev tile (or v phase) reads complete
        *(float4*)&stg[0][srow][scol] = rg;
        if (tt < 7)
            rg = *(const float4*)(Sb + sbase + (size_t)((tt + 1) * 16 + srow) * DVH + scol);
        __syncthreads();               // tile staged
        #pragma unroll
        for (int q = 0; q < 16; q++) {
            int kk = tt * 16 + q;
            float4 s4 = *(const float4*)&stg[0][q][c4];
            float a0 = rt[t0][kk], a1 = rt[t0 + 1][kk];
            acc[0][0] += a0 * s4.x; acc[0][1] += a0 * s4.y;
            acc[0][2] += a0 * s4.z; acc[0][3] += a0 * s4.w;
            acc[1][0] += a1 * s4.x; acc[1][1] += a1 * s4.y;
            acc[1][2] += a1 * s4.z; acc[1][3] += a1 * s4.w;
        }
    }
    // groupnorm + affine + silu(g) gate, y f32 in place over v
    int cbase = h * DVH + c4;
    float4 gwA = *(const float4*)(gnw + cbase);
    float4 gbA = *(const float4*)(gnb + cbase);
    float gwv[4] = {gwA.x, gwA.y, gwA.z, gwA.w};
    float gbv[4] = {gbA.x, gbA.y, gbA.z, gbA.w};
    #pragma unroll
    for (int i = 0; i < 2; i++) {
        float sum = 0.f, sq = 0.f;
        #pragma unroll
        for (int jj = 0; jj < 4; jj++) {
            sum += acc[i][jj];
            sq  += acc[i][jj] * acc[i][jj];
        }
        #pragma unroll
        for (int m = 1; m < 64; m <<= 1) {
            sum += __shfl_xor(sum, m);
            sq  += __shfl_xor(sq, m);
        }
        float mean = sum * (1.f / DVH);
        float var = sq * (1.f / DVH) - mean * mean;
        float inv = rsqrtf(var + 1e-5f);
        size_t mrow = (size_t)(tok0 + t0 + i) * VDIM + cbase;
        float4 gA = *(const float4*)(gb_ + mrow);
        float gv[4] = {gA.x, gA.y, gA.z, gA.w};
        float o4[4];
        #pragma unroll
        for (int jj = 0; jj < 4; jj++) {
            float gg = gv[jj];
            float sig = 1.f / (1.f + __expf(-gg));
            o4[jj] = ((acc[i][jj] - mean) * inv * gwv[jj] + gbv[jj]) * (gg * sig);
        }
        *(float4*)(vb + mrow) = make_float4(o4[0], o4[1], o4[2], o4[3]);
    }
}

// ---------------------------------------------------------------------------
// Kernel 6: output GEMM, split precision. 64x128 tile. B-side staged via
// global_load_lds width=16 into LINEAR LDS [128][32] (512 chunks: each wave
// stages 2x64 chunks per buffer); A reg-staged (f2u hi/lo) into 40-pad LDS.
// ---------------------------------------------------------------------------
__global__ __launch_bounds__(256) void k_gemm_out(
    const float* __restrict__ A, const bf16* __restrict__ Bh,
    const bf16* __restrict__ Bl, float* __restrict__ C, int M, int N, int K)
{
    __shared__ unsigned short Ah[64 * 40];
    __shared__ unsigned short Al[64 * 40];
    __shared__ unsigned short Bhs[128 * 32];
    __shared__ unsigned short Bls[128 * 32];
    int tid = threadIdx.x;
    int bm = blockIdx.x * 64, bn = blockIdx.y * 128;
    int lane = tid & 63, w = tid >> 6;
    int wr = w >> 1, wc = w & 1;
    const unsigned short* Bh16 = (const unsigned short*)Bh;
    const unsigned short* Bl16 = (const unsigned short*)Bl;
    f32x4 acc[2][4];
    #pragma unroll
    for (int i = 0; i < 2; i++)
        #pragma unroll
        for (int j = 0; j < 4; j++)
            acc[i][j] = (f32x4){0.f, 0.f, 0.f, 0.f};
    int arow = tid >> 2, acol = (tid & 3) * 8;     // A: 64x32 f32, 8 per thread
    int fr = lane & 15, kb = (lane >> 4) * 8;
    int c0w = w * 128;
    for (int k0 = 0; k0 < K; k0 += 32) {
        float4 t4a = *(const float4*)(A + (size_t)(bm + arow) * K + k0 + acol);
        float4 t4b = *(const float4*)(A + (size_t)(bm + arow) * K + k0 + acol + 4);
        __syncthreads();                   // prev iteration frag reads complete
        #pragma unroll
        for (int q = 0; q < 2; q++) {
            int cb = c0w + q * 64;         // wave-uniform
            int c = cb + lane;
            int row = c >> 2, co = (c & 3) * 8;
            const unsigned short* gh2 = Bh16 + (size_t)(bn + row) * K + k0 + co;
            const unsigned short* gl2 = Bl16 + (size_t)(bn + row) * K + k0 + co;
            __builtin_amdgcn_global_load_lds(
                (const __attribute__((address_space(1))) void*)gh2,
                (__attribute__((address_space(3))) void*)(Bhs + cb * 8), 16, 0, 0);
            __builtin_amdgcn_global_load_lds(
                (const __attribute__((address_space(1))) void*)gl2,
                (__attribute__((address_space(3))) void*)(Bls + cb * 8), 16, 0, 0);
        }
        float av[8] = {t4a.x, t4a.y, t4a.z, t4a.w, t4b.x, t4b.y, t4b.z, t4b.w};
        alignas(16) unsigned short th[8], tl[8];
        #pragma unroll
        for (int q = 0; q < 8; q++) {
            unsigned short hu = f2u(av[q]);
            th[q] = hu;
            tl[q] = f2u(av[q] - u2f(hu));
        }
        *(uint4*)(Ah + arow * 40 + acol) = *(const uint4*)&th[0];
        *(uint4*)(Al + arow * 40 + acol) = *(const uint4*)&tl[0];
        __syncthreads();                   // gload_lds + A writes complete
        bf16x8 afh[2], afl[2], bfh[4], bfl[4];
        #pragma unroll
        for (int i = 0; i < 2; i++) {
            afh[i] = *(const bf16x8*)(Ah + (wr * 32 + i * 16 + fr) * 40 + kb);
            afl[i] = *(const bf16x8*)(Al + (wr * 32 + i * 16 + fr) * 40 + kb);
        }
        #pragma unroll
        for (int j = 0; j < 4; j++) {
            bfh[j] = *(const bf16x8*)(Bhs + (wc * 64 + j * 16 + fr) * 32 + kb);
            bfl[j] = *(const bf16x8*)(Bls + (wc * 64 + j * 16 + fr) * 32 + kb);
        }
        #pragma unroll
        for (int i = 0; i < 2; i++)
            #pragma unroll
            for (int j = 0; j < 4; j++) {
                acc[i][j] = __builtin_amdgcn_mfma_f32_16x16x32_bf16(afh[i], bfh[j], acc[i][j], 0, 0, 0);
                acc[i][j] = __builtin_amdgcn_mfma_f32_16x16x32_bf16(afl[i], bfh[j], acc[i][j], 0, 0, 0);
                acc[i][j] = __builtin_amdgcn_mfma_f32_16x16x32_bf16(afh[i], bfl[j], acc[i][j], 0, 0, 0);
            }
    }
    int er = (lane >> 4) * 4, ec = lane & 15;
    #pragma unroll
    for (int i = 0; i < 2; i++) {
        int gr = bm + wr * 32 + i * 16 + er;
        #pragma unroll
        for (int j = 0; j < 4; j++) {
            int gc = bn + wc * 64 + j * 16 + ec;
            #pragma unroll
            for (int q = 0; q < 4; q++)
                C[(size_t)(gr + q) * N + gc] = acc[i][j][q];
        }
    }
}

// ---------------------------------------------------------------------------
extern "C" void kernel_launch(void* const* d_in, const int* in_sizes, int n_in,
                              void* d_out, int out_size, void* d_ws, size_t ws_size,
                              hipStream_t stream)
{
    const float* h        = (const float*)d_in[0];
    const float* x_mu     = (const float*)d_in[1];
    const float* xl_w1    = (const float*)d_in[2];
    const float* xl_w2    = (const float*)d_in[3];
    const float* xl_b2    = (const float*)d_in[4];
    const float* x_out_w  = (const float*)d_in[5];
    const float* x_bias   = (const float*)d_in[6];
    const float* r_w      = (const float*)d_in[7];
    const float* w_w1     = (const float*)d_in[8];
    const float* w_w2     = (const float*)d_in[9];
    const float* w_b      = (const float*)d_in[10];
    const float* k_w      = (const float*)d_in[11];
    const float* v_w      = (const float*)d_in[12];
    const float* g_w      = (const float*)d_in[13];
    const float* bonus    = (const float*)d_in[14];
    const float* gn_w     = (const float*)d_in[15];
    const float* gn_b     = (const float*)d_in[16];
    const float* o_w      = (const float*)d_in[17];
    float* out = (float*)d_out;

    // Workspace overlay: total 35,733,504 floats = 142.9 MB (proven size)
    float* ws = (float*)d_ws;
    bf16*  wbf  = (bf16*)ws;                       // 8,388,608 bf16 = 4,194,304 slots
    float* rbuf = ws + 4194304;                    // 2,097,152
    float* vbuf = ws + 6291456;                    // 4,194,304 (y f32 in place later)
    float* gbuf = ws + 10485760;                   // 4,194,304
    float* kbuf = ws + 14680064;                   // 2,097,152
    float* ebuf = ws + 16777216;                   // 2,097,152
    float* ubuf = ws + 18874368;                   // 16,384
    float* Dbuf = ws + 18890752;                   // 65,536
    float* BIG  = ws + 18956288;                   // 16,777,216 (X phase / Mbuf)

    // weight hi/lo (bf16 element offsets within wbf)
    bf16* rwb_h = wbf;                  // 524,288
    bf16* kwb_h = wbf + 524288;
    bf16* vwb_h = wbf + 1048576;        // 1,048,576
    bf16* gwb_h = wbf + 2097152;
    bf16* owb_h = wbf + 3145728;
    bf16* rwb_l = wbf + 4194304;
    bf16* kwb_l = wbf + 4718592;
    bf16* vwb_l = wbf + 5242880;
    bf16* gwb_l = wbf + 6291456;
    bf16* owb_l = wbf + 7340032;

    // X phase inside BIG (each bf16 X = 2,097,152 float slots)
    float* Xw = BIG;                           // f32 [0 .. 4,194,304)
    bf16*  Xr = (bf16*)(BIG + 4194304);
    bf16*  Xk = (bf16*)(BIG + 6291456);
    bf16*  Xv = (bf16*)(BIG + 8388608);
    bf16*  Xg = (bf16*)(BIG + 10485760);
    float* x1   = BIG + 12582912;              // 655,360  (dead after mix)
    float* t0bf = BIG + 13238272;              // 131,072  (dead after k_x1b)
    float* w1p  = BIG + 12582912;              // 2,097,152 (after x1/t0 dead; dead before Mbuf)
    float* Mbuf = BIG;                         // full 16,777,216 after X dead
    float* ybuf = vbuf;                        // y f32 in place over v

    // weight conversion (hi/lo pairs), single launch
    k_f2b2_all<<<2048, 256, 0, stream>>>(r_w, k_w, v_w, g_w, o_w,
                                         rwb_h, rwb_l, kwb_h, kwb_l,
                                         vwb_h, vwb_l, gwb_h, gwb_l,
                                         owb_h, owb_l);

    // x1 path: MFMA phase-1 + small phase-2
    k_x1mm<<<NTOK / 64, 256, 0, stream>>>(h, x_mu, xl_w1, t0bf);
    k_x1b<<<NTOK / 64, 256, 0, stream>>>(t0bf, xl_w2, xl_b2, x1);

    // mix: f32 w-slice + MFMA bf16 four-slice
    k_mixw<<<dim3(NTOK / 64, HH / 64), 256, 0, stream>>>(h, x1, x_out_w, x_bias, Xw);
    k_mix4<<<dim3(NTOK / 64, HH / 64), 256, 0, stream>>>(h, x1, x_out_w, x_bias,
                                                         Xr, Xk, Xv, Xg);

    // projections: ALL FOUR hi/lo MFMA GEMMs in one launch (128x128 tiles,
    // global_load_lds staging); split-K f32 w path
    k_gemm_hl4<<<dim3(NTOK / 128, VDIM / 128, 4), 256, 0, stream>>>(
        Xr, rwb_h, rwb_l, rbuf,
        Xk, kwb_h, kwb_l, kbuf,
        Xv, vwb_h, vwb_l, vbuf,
        Xg, gwb_h, gwb_l, gbuf, NTOK, HH);
    k_w1<<<dim3(NTOK / 64, WKS), 256, 0, stream>>>(Xw, w_w1, w1p);
    k_we<<<dim3(NTOK / 64, KDIM / 64), 256, 0, stream>>>(w1p, w_w2, w_b, ebuf);

    k_chunkA1<<<dim3(BB * NHD, NCK), 256, 0, stream>>>(ebuf, rbuf, kbuf, vbuf,
                                                       bonus, ubuf, Mbuf, Dbuf);
    k_chunkB<<<dim3(BB * NHD, NCK), 256, 0, stream>>>(Mbuf, Dbuf);
    k_chunkCG<<<dim3(BB * NHD, NCK), 1024, 0, stream>>>(rbuf, kbuf, vbuf, ubuf, Mbuf,
                                                        gbuf, gn_w, gn_b);

    k_gemm_out<<<dim3(NTOK / 64, HH / 128), 256, 0, stream>>>(ybuf, owb_h, owb_l, out, NTOK, HH, VDIM);
}

// Round 24
// 279.125 us; speedup vs baseline: 1.0864x; 1.0415x over previous
//
#include <hip/hip_runtime.h>
#include <hip/hip_bf16.h>
#include <math.h>

// Problem constants
static constexpr int BB = 4;
static constexpr int TT = 1024;
static constexpr int HH = 1024;
static constexpr int NHD = 4;
static constexpr int KDIM = 512;
static constexpr int VDIM = 1024;
static constexpr int DKH = 128;   // KD / NH
static constexpr int DVH = 256;   // VD / NH
static constexpr int RR = 32;
static constexpr int R5D = 160;
static constexpr int GG = 64;
static constexpr int NTOK = BB * TT;   // 4096
static constexpr int CK = 32;          // chunk length
static constexpr int NCK = TT / CK;    // 32 chunks per sequence
static constexpr int WKS = 8;          // split-K factor for the w1 gemm

typedef __bf16 bf16x8 __attribute__((ext_vector_type(8)));
typedef float f32x4 __attribute__((ext_vector_type(4)));
typedef __hip_bfloat16 bf16;

static __device__ inline unsigned short f2u(float v) {
    __hip_bfloat16 b = __float2bfloat16(v);
    unsigned short u; __builtin_memcpy(&u, &b, 2); return u;
}
static __device__ inline float u2f(unsigned short u) {
    __hip_bfloat16 b; __builtin_memcpy(&b, &u, 2); return __bfloat162float(b);
}

// ---------------------------------------------------------------------------
// Kernel 0: f32 -> bf16 hi/lo pairs, all 5 weights in one launch
// ---------------------------------------------------------------------------
__global__ __launch_bounds__(256) void k_f2b2_all(
    const float* __restrict__ r_w, const float* __restrict__ k_w,
    const float* __restrict__ v_w, const float* __restrict__ g_w,
    const float* __restrict__ o_w,
    bf16* __restrict__ rh, bf16* __restrict__ rl,
    bf16* __restrict__ kh, bf16* __restrict__ kl,
    bf16* __restrict__ vh, bf16* __restrict__ vl,
    bf16* __restrict__ gh, bf16* __restrict__ gl,
    bf16* __restrict__ oh, bf16* __restrict__ ol)
{
    size_t g = ((size_t)blockIdx.x * 256 + threadIdx.x) * 8;
    const float* s; bf16 *hi, *lo; size_t off;
    if (g < 524288)       { s = r_w; hi = rh; lo = rl; off = g; }
    else if (g < 1048576) { s = k_w; hi = kh; lo = kl; off = g - 524288; }
    else if (g < 2097152) { s = v_w; hi = vh; lo = vl; off = g - 1048576; }
    else if (g < 3145728) { s = g_w; hi = gh; lo = gl; off = g - 2097152; }
    else                  { s = o_w; hi = oh; lo = ol; off = g - 3145728; }
    #pragma unroll
    for (int j = 0; j < 8; j++) {
        float v = s[off + j];
        bf16 hb = __float2bfloat16(v);
        hi[off + j] = hb;
        lo[off + j] = __float2bfloat16(v - __bfloat162float(hb));
    }
}

// ---------------------------------------------------------------------------
// Kernel 1a (k_x1mm): t0[4096x32] = tanh( x_lerp @ w1^T ) via bf16 MFMA.
// ---------------------------------------------------------------------------
__global__ __launch_bounds__(256) void k_x1mm(
    const float* __restrict__ h, const float* __restrict__ mu,
    const float* __restrict__ w1, float* __restrict__ t0)
{
    __shared__ unsigned short Al[64][40];
    __shared__ unsigned short Bl[32][40];
    int tid = threadIdx.x;
    int m0 = blockIdx.x * 64;
    int lane = tid & 63, w = tid >> 6;
    f32x4 acc[2];
    acc[0] = (f32x4){0.f, 0.f, 0.f, 0.f};
    acc[1] = (f32x4){0.f, 0.f, 0.f, 0.f};
    int ar = tid >> 2, ac0 = (tid & 3) * 8;        // A stage: 64x32, 8 per thread
    int br = tid >> 3, bc0 = (tid & 7) * 4;        // B stage: 32x32, 4 per thread
    int fr = lane & 15, kb = lane >> 4;
    int mrow = m0 + ar;
    int trow = mrow & (TT - 1);
    const float* hp = h + (size_t)mrow * HH;
    for (int k0 = 0; k0 < HH; k0 += 32) {
        float av[8];
        #pragma unroll
        for (int j = 0; j < 8; j += 4) {
            float4 c4 = *(const float4*)(hp + k0 + ac0 + j);
            float4 p4 = make_float4(0.f, 0.f, 0.f, 0.f);
            if (trow > 0) p4 = *(const float4*)(hp + k0 + ac0 + j - HH);
            float4 m4 = *(const float4*)(mu + k0 + ac0 + j);
            av[j + 0] = c4.x + (p4.x - c4.x) * m4.x;
            av[j + 1] = c4.y + (p4.y - c4.y) * m4.y;
            av[j + 2] = c4.z + (p4.z - c4.z) * m4.z;
            av[j + 3] = c4.w + (p4.w - c4.w) * m4.w;
        }
        float4 b4 = *(const float4*)(w1 + (size_t)br * HH + k0 + bc0);
        __syncthreads();
        #pragma unroll
        for (int j = 0; j < 8; j++) Al[ar][ac0 + j] = f2u(av[j]);
        Bl[br][bc0 + 0] = f2u(b4.x); Bl[br][bc0 + 1] = f2u(b4.y);
        Bl[br][bc0 + 2] = f2u(b4.z); Bl[br][bc0 + 3] = f2u(b4.w);
        __syncthreads();
        bf16x8 af = *(const bf16x8*)(&Al[w * 16 + fr][kb * 8]);
        bf16x8 bf0 = *(const bf16x8*)(&Bl[fr][kb * 8]);
        bf16x8 bf1 = *(const bf16x8*)(&Bl[16 + fr][kb * 8]);
        acc[0] = __builtin_amdgcn_mfma_f32_16x16x32_bf16(af, bf0, acc[0], 0, 0, 0);
        acc[1] = __builtin_amdgcn_mfma_f32_16x16x32_bf16(af, bf1, acc[1], 0, 0, 0);
    }
    int er = (lane >> 4) * 4, ec = lane & 15;
    #pragma unroll
    for (int j = 0; j < 2; j++) {
        #pragma unroll
        for (int q = 0; q < 4; q++) {
            int gr = m0 + w * 16 + er + q;
            t0[(size_t)gr * RR + j * 16 + ec] = tanhf(acc[j][q]);
        }
    }
}

// ---------------------------------------------------------------------------
// Kernel 1b (k_x1b): x1[4096x160] = tanh( t0 @ w2^T + b2 ).  K=32.
// ---------------------------------------------------------------------------
__global__ __launch_bounds__(256) void k_x1b(
    const float* __restrict__ t0, const float* __restrict__ w2,
    const float* __restrict__ b2, float* __restrict__ x1out)
{
    __shared__ float t0s[64][33];
    __shared__ float w2s[R5D * RR];
    __shared__ float b2s[R5D];
    int tid = threadIdx.x;
    int m0 = blockIdx.x * 64;
    {
        int row = tid >> 2, c0 = (tid & 3) * 8;
        float4 a = *(const float4*)(t0 + (size_t)(m0 + row) * RR + c0);
        float4 b = *(const float4*)(t0 + (size_t)(m0 + row) * RR + c0 + 4);
        t0s[row][c0 + 0] = a.x; t0s[row][c0 + 1] = a.y;
        t0s[row][c0 + 2] = a.z; t0s[row][c0 + 3] = a.w;
        t0s[row][c0 + 4] = b.x; t0s[row][c0 + 5] = b.y;
        t0s[row][c0 + 6] = b.z; t0s[row][c0 + 7] = b.w;
    }
    for (int i = tid; i < R5D * RR; i += 256) w2s[i] = w2[i];
    if (tid < R5D) b2s[tid] = b2[tid];
    __syncthreads();
    int tt = tid & 63, cg = tid >> 6;
    float t0r[32];
    #pragma unroll
    for (int q = 0; q < 32; q++) t0r[q] = t0s[tt][q];
    float* xo = x1out + (size_t)(m0 + tt) * R5D + cg * 40;
    for (int c = 0; c < 40; c++) {
        const float* wr = w2s + (cg * 40 + c) * RR;
        float s = b2s[cg * 40 + c];
        #pragma unroll
        for (int q = 0; q < 32; q++) s += t0r[q] * wr[q];
        xo[c] = tanhf(s);
    }
}

// ---------------------------------------------------------------------------
// Kernel 2a (k_mixw): n=1 slice only (w path, f32 exact).
// ---------------------------------------------------------------------------
__global__ __launch_bounds__(256) void k_mixw(
    const float* __restrict__ h, const float* __restrict__ x1,
    const float* __restrict__ xow, const float* __restrict__ xb,
    float* __restrict__ xw)
{
    int m0 = blockIdx.x * 64;
    int h0 = blockIdx.y * 64;
    int tid = threadIdx.x;
    __shared__ float x1sT[32][68];
    __shared__ float xosT[32][68];
    int rr = tid & 63, cg = tid >> 6;    // cg = wave id, 8 cols each
    {
        const float* xp = x1 + (size_t)(m0 + rr) * R5D + 32 + cg * 8;
        const float* wp = xow + (size_t)(h0 + rr) * R5D + 32 + cg * 8;
        float4 a0 = *(const float4*)xp, a1 = *(const float4*)(xp + 4);
        float4 b0 = *(const float4*)wp, b1 = *(const float4*)(wp + 4);
        x1sT[cg * 8 + 0][rr] = a0.x; x1sT[cg * 8 + 1][rr] = a0.y;
        x1sT[cg * 8 + 2][rr] = a0.z; x1sT[cg * 8 + 3][rr] = a0.w;
        x1sT[cg * 8 + 4][rr] = a1.x; x1sT[cg * 8 + 5][rr] = a1.y;
        x1sT[cg * 8 + 6][rr] = a1.z; x1sT[cg * 8 + 7][rr] = a1.w;
        xosT[cg * 8 + 0][rr] = b0.x; xosT[cg * 8 + 1][rr] = b0.y;
        xosT[cg * 8 + 2][rr] = b0.z; xosT[cg * 8 + 3][rr] = b0.w;
        xosT[cg * 8 + 4][rr] = b1.x; xosT[cg * 8 + 5][rr] = b1.y;
        xosT[cg * 8 + 6][rr] = b1.z; xosT[cg * 8 + 7][rr] = b1.w;
    }
    int tx = tid & 15, ty = tid >> 4;
    float creg[4][4], dreg[4][4];
    #pragma unroll
    for (int i = 0; i < 4; i++) {
        int m = m0 + ty * 4 + i;
        int t = m & (TT - 1);
        const float* hp = h + (size_t)m * HH + h0 + tx * 4;
        float4 c4 = *(const float4*)hp;
        float4 p4 = make_float4(0.f, 0.f, 0.f, 0.f);
        if (t > 0) p4 = *(const float4*)(hp - HH);
        creg[i][0] = c4.x; dreg[i][0] = p4.x - c4.x;
        creg[i][1] = c4.y; dreg[i][1] = p4.y - c4.y;
        creg[i][2] = c4.z; dreg[i][2] = p4.z - c4.z;
        creg[i][3] = c4.w; dreg[i][3] = p4.w - c4.w;
    }
    __syncthreads();
    float acc[4][4] = {};
    #pragma unroll
    for (int r2 = 0; r2 < 32; r2++) {
        float4 a4 = *(const float4*)&x1sT[r2][ty * 4];
        float4 b4 = *(const float4*)&xosT[r2][tx * 4];
        float aa[4] = {a4.x, a4.y, a4.z, a4.w};
        float bb[4] = {b4.x, b4.y, b4.z, b4.w};
        #pragma unroll
        for (int i = 0; i < 4; i++)
            #pragma unroll
            for (int j = 0; j < 4; j++)
                acc[i][j] += aa[i] * bb[j];
    }
    float4 xb4 = *(const float4*)(xb + HH + h0 + tx * 4);   // n=1 row of x_bias
    float xbv[4] = {xb4.x, xb4.y, xb4.z, xb4.w};
    #pragma unroll
    for (int i = 0; i < 4; i++) {
        size_t idx = (size_t)(m0 + ty * 4 + i) * HH + h0 + tx * 4;
        float v[4];
        #pragma unroll
        for (int j = 0; j < 4; j++)
            v[j] = creg[i][j] + dreg[i][j] * (acc[i][j] + xbv[j]);
        *(float4*)(xw + idx) = make_float4(v[0], v[1], v[2], v[3]);
    }
}

// ---------------------------------------------------------------------------
// Kernel 2b (k_mix4): n in {0,2,3,4} via MFMA. B-side (xow) staged in LDS,
// compacted to the 4 used 32-col slots: xs[64][132] (33.8 KB, 2-way-free
// bank pattern, 16B-aligned). Same values through same f2u path -> identical.
// ---------------------------------------------------------------------------
__global__ __launch_bounds__(256) void k_mix4(
    const float* __restrict__ h, const float* __restrict__ x1,
    const float* __restrict__ xow, const float* __restrict__ xb,
    bf16* __restrict__ xr, bf16* __restrict__ xk,
    bf16* __restrict__ xv, bf16* __restrict__ xg)
{
    __shared__ float xs[64][132];      // slot s holds xow cols ns[s]*32..+31
    int m0 = blockIdx.x * 64;
    int h0 = blockIdx.y * 64;
    int tid = threadIdx.x;
    int lane = tid & 63, w = tid >> 6;
    int fr = lane & 15, kb = (lane >> 4) * 8;
    int er = (lane >> 4) * 4, ec = lane & 15;
    const int ns[4] = {0, 2, 3, 4};
    // stage xow tile: 64 rows x 4 slots x 32 cols = 2048 float4 groups
    #pragma unroll
    for (int it = 0; it < 8; it++) {
        int idx = it * 256 + tid;
        int row = idx >> 5;            // 0..63
        int cg = idx & 31;             // float4 col group
        int slot = cg >> 3, wi = (cg & 7) * 4;
        float4 v = *(const float4*)(xow + (size_t)(h0 + row) * R5D + ns[slot] * 32 + wi);
        *(float4*)&xs[row][slot * 32 + wi] = v;
    }
    float creg[4][4], dreg[4][4];
    #pragma unroll
    for (int q = 0; q < 4; q++) {
        int m = m0 + w * 16 + er + q;
        int t = m & (TT - 1);
        const float* hp = h + (size_t)m * HH;
        #pragma unroll
        for (int j = 0; j < 4; j++) {
            int hh = h0 + j * 16 + ec;
            float c = hp[hh];
            float p = (t > 0) ? hp[hh - HH] : 0.f;
            creg[q][j] = c;
            dreg[q][j] = p - c;
        }
    }
    __syncthreads();
    bf16* outs[4] = {xr, xk, xv, xg};
    #pragma unroll
    for (int ni = 0; ni < 4; ni++) {
        int n = ns[ni];
        const float* ap = x1 + (size_t)(m0 + w * 16 + fr) * R5D + n * 32 + kb;
        float4 a0 = *(const float4*)ap;
        float4 a1 = *(const float4*)(ap + 4);
        alignas(16) unsigned short ta[8];
        ta[0] = f2u(a0.x); ta[1] = f2u(a0.y); ta[2] = f2u(a0.z); ta[3] = f2u(a0.w);
        ta[4] = f2u(a1.x); ta[5] = f2u(a1.y); ta[6] = f2u(a1.z); ta[7] = f2u(a1.w);
        bf16x8 af = *(const bf16x8*)ta;
        f32x4 accj[4];
        #pragma unroll
        for (int j = 0; j < 4; j++) {
            const float* bp = &xs[j * 16 + fr][ni * 32 + kb];
            float4 b0 = *(const float4*)bp;
            float4 b1 = *(const float4*)(bp + 4);
            alignas(16) unsigned short tb[8];
            tb[0] = f2u(b0.x); tb[1] = f2u(b0.y); tb[2] = f2u(b0.z); tb[3] = f2u(b0.w);
            tb[4] = f2u(b1.x); tb[5] = f2u(b1.y); tb[6] = f2u(b1.z); tb[7] = f2u(b1.w);
            bf16x8 bf_ = *(const bf16x8*)tb;
            f32x4 z = (f32x4){0.f, 0.f, 0.f, 0.f};
            accj[j] = __builtin_amdgcn_mfma_f32_16x16x32_bf16(af, bf_, z, 0, 0, 0);
        }
        bf16* op = outs[ni];
        #pragma unroll
        for (int j = 0; j < 4; j++) {
            float xbv = xb[n * HH + h0 + j * 16 + ec];
            #pragma unroll
            for (int q = 0; q < 4; q++) {
                float val = creg[q][j] + dreg[q][j] * (accj[j][q] + xbv);
                op[(size_t)(m0 + w * 16 + er + q) * HH + h0 + j * 16 + ec] =
                    __float2bfloat16(val);
            }
        }
    }
}

// ---------------------------------------------------------------------------
// Kernel 3a (k_gemm_hl4): FOUR hi/lo GEMMs in one launch (z: 0=r,1=k N=512;
// 2=v,3=g N=1024). 128x128 tile. Staging via global_load_lds width=16 into
// LINEAR LDS [128][32] (wave-uniform dest + lane*16B). m97-proven structure.
// ---------------------------------------------------------------------------
__global__ __launch_bounds__(256) void k_gemm_hl4(
    const bf16* __restrict__ A0, const bf16* __restrict__ Bh0,
    const bf16* __restrict__ Bl0, float* __restrict__ C0,
    const bf16* __restrict__ A1, const bf16* __restrict__ Bh1,
    const bf16* __restrict__ Bl1, float* __restrict__ C1,
    const bf16* __restrict__ A2, const bf16* __restrict__ Bh2,
    const bf16* __restrict__ Bl2, float* __restrict__ C2,
    const bf16* __restrict__ A3, const bf16* __restrict__ Bh3,
    const bf16* __restrict__ Bl3, float* __restrict__ C3,
    int M, int K)
{
    int z = blockIdx.z;
    const bf16* A;
    const bf16* Bh;
    const bf16* Bl;
    float* C;
    int N;
    if (z == 0)      { A = A0; Bh = Bh0; Bl = Bl0; C = C0; N = KDIM; }
    else if (z == 1) { A = A1; Bh = Bh1; Bl = Bl1; C = C1; N = KDIM; }
    else if (z == 2) { A = A2; Bh = Bh2; Bl = Bl2; C = C2; N = VDIM; }
    else             { A = A3; Bh = Bh3; Bl = Bl3; C = C3; N = VDIM; }
    int bn = blockIdx.y * 128;
    if (bn >= N) return;
    __shared__ unsigned short As[128 * 32];
    __shared__ unsigned short Bhs[128 * 32];
    __shared__ unsigned short Bls[128 * 32];
    int tid = threadIdx.x;
    int bm = blockIdx.x * 128;
    int lane = tid & 63, w = tid >> 6;
    int wr = w >> 1, wc = w & 1;
    const unsigned short* A16 = (const unsigned short*)A;
    const unsigned short* Bh16 = (const unsigned short*)Bh;
    const unsigned short* Bl16 = (const unsigned short*)Bl;
    f32x4 acc[4][4];
    #pragma unroll
    for (int i = 0; i < 4; i++)
        #pragma unroll
        for (int j = 0; j < 4; j++)
            acc[i][j] = (f32x4){0.f, 0.f, 0.f, 0.f};
    int fr = lane & 15, kb = (lane >> 4) * 8;
    // chunk mapping: chunk c (16B) covers row c>>2, col (c&3)*8 shorts.
    int c0w = w * 128;
    for (int k0 = 0; k0 < K; k0 += 32) {
        #pragma unroll
        for (int q = 0; q < 2; q++) {
            int cb = c0w + q * 64;            // wave-uniform
            int c = cb + lane;
            int row = c >> 2, co = (c & 3) * 8;
            const unsigned short* ga = A16 + (size_t)(bm + row) * K + k0 + co;
            const unsigned short* gh2 = Bh16 + (size_t)(bn + row) * K + k0 + co;
            const unsigned short* gl2 = Bl16 + (size_t)(bn + row) * K + k0 + co;
            __builtin_amdgcn_global_load_lds(
                (const __attribute__((address_space(1))) void*)ga,
                (__attribute__((address_space(3))) void*)(As + cb * 8), 16, 0, 0);
            __builtin_amdgcn_global_load_lds(
                (const __attribute__((address_space(1))) void*)gh2,
                (__attribute__((address_space(3))) void*)(Bhs + cb * 8), 16, 0, 0);
            __builtin_amdgcn_global_load_lds(
                (const __attribute__((address_space(1))) void*)gl2,
                (__attribute__((address_space(3))) void*)(Bls + cb * 8), 16, 0, 0);
        }
        __syncthreads();
        bf16x8 af[4], bfh[4], bfl[4];
        #pragma unroll
        for (int i = 0; i < 4; i++) {
            af[i]  = *(const bf16x8*)(As + (wr * 64 + i * 16 + fr) * 32 + kb);
            bfh[i] = *(const bf16x8*)(Bhs + (wc * 64 + i * 16 + fr) * 32 + kb);
            bfl[i] = *(const bf16x8*)(Bls + (wc * 64 + i * 16 + fr) * 32 + kb);
        }
        #pragma unroll
        for (int i = 0; i < 4; i++)
            #pragma unroll
            for (int j = 0; j < 4; j++) {
                acc[i][j] = __builtin_amdgcn_mfma_f32_16x16x32_bf16(af[i], bfh[j], acc[i][j], 0, 0, 0);
                acc[i][j] = __builtin_amdgcn_mfma_f32_16x16x32_bf16(af[i], bfl[j], acc[i][j], 0, 0, 0);
            }
        __syncthreads();
    }
    int er = (lane >> 4) * 4, ec = lane & 15;
    #pragma unroll
    for (int i = 0; i < 4; i++) {
        int gr = bm + wr * 64 + i * 16 + er;
        #pragma unroll
        for (int j = 0; j < 4; j++) {
            int gc = bn + wc * 64 + j * 16 + ec;
            #pragma unroll
            for (int q = 0; q < 4; q++)
                C[(size_t)(gr + q) * N + gc] = acc[i][j][q];
        }
    }
}

// ---------------------------------------------------------------------------
// Kernel 3b (k_w1): split-K partial GEMM for the w path.
// ---------------------------------------------------------------------------
__global__ __launch_bounds__(256) void k_w1(
    const float* __restrict__ A, const float* __restrict__ Bm,
    float* __restrict__ P)
{
    __shared__ float As[16][68];
    __shared__ float Bs[16][68];
    int tid = threadIdx.x;
    int bm = blockIdx.x * 64;
    int ks = blockIdx.y;
    int kbase = ks * (HH / WKS);       // 128-wide K slice
    int tx = tid & 15, ty = tid >> 4;
    int lr = tid >> 2;
    int lk = (tid & 3) * 4;
    float acc[4][4] = {};
    for (int k0 = 0; k0 < HH / WKS; k0 += 16) {
        float4 av = *(const float4*)(A + (size_t)(bm + lr) * HH + kbase + k0 + lk);
        float4 bv = *(const float4*)(Bm + (size_t)lr * HH + kbase + k0 + lk);
        As[lk + 0][lr] = av.x; As[lk + 1][lr] = av.y;
        As[lk + 2][lr] = av.z; As[lk + 3][lr] = av.w;
        Bs[lk + 0][lr] = bv.x; Bs[lk + 1][lr] = bv.y;
        Bs[lk + 2][lr] = bv.z; Bs[lk + 3][lr] = bv.w;
        __syncthreads();
        #pragma unroll
        for (int kk = 0; kk < 16; kk++) {
            float4 a4 = *(const float4*)&As[kk][ty * 4];
            float4 b4 = *(const float4*)&Bs[kk][tx * 4];
            float aa[4] = {a4.x, a4.y, a4.z, a4.w};
            float bb[4] = {b4.x, b4.y, b4.z, b4.w};
            #pragma unroll
            for (int i = 0; i < 4; i++)
                #pragma unroll
                for (int j = 0; j < 4; j++)
                    acc[i][j] += aa[i] * bb[j];
        }
        __syncthreads();
    }
    #pragma unroll
    for (int i = 0; i < 4; i++) {
        size_t row = (size_t)ks * NTOK + bm + ty * 4 + i;
        *(float4*)(P + row * GG + tx * 4) =
            make_float4(acc[i][0], acc[i][1], acc[i][2], acc[i][3]);
    }
}

// ---------------------------------------------------------------------------
// Kernel 3c (k_we): e = exp( tanh(sum_ks P) @ w_w2^T + w_b ).
// ---------------------------------------------------------------------------
__global__ __launch_bounds__(256) void k_we(
    const float* __restrict__ P, const float* __restrict__ w_w2,
    const float* __restrict__ w_b, float* __restrict__ eb)
{
    __shared__ float As[64][65];
    __shared__ float Bs[64][65];
    int tid = threadIdx.x;
    int bm = blockIdx.x * 64, bn = blockIdx.y * 64;
    {
        int r = tid >> 2, c0 = (tid & 3) * 16;
        float s[16];
        #pragma unroll
        for (int j = 0; j < 16; j++) s[j] = 0.f;
        for (int ks = 0; ks < WKS; ks++) {
            const float* pp = P + ((size_t)ks * NTOK + bm + r) * GG + c0;
            #pragma unroll
            for (int j = 0; j < 16; j += 4) {
                float4 v = *(const float4*)(pp + j);
                s[j + 0] += v.x; s[j + 1] += v.y; s[j + 2] += v.z; s[j + 3] += v.w;
            }
        }
        #pragma unroll
        for (int j = 0; j < 16; j++) As[r][c0 + j] = tanhf(s[j]);
        const float* bp = w_w2 + (size_t)(bn + r) * GG + c0;
        #pragma unroll
        for (int j = 0; j < 16; j += 4) {
            float4 v = *(const float4*)(bp + j);
            Bs[r][c0 + j + 0] = v.x; Bs[r][c0 + j + 1] = v.y;
            Bs[r][c0 + j + 2] = v.z; Bs[r][c0 + j + 3] = v.w;
        }
    }
    __syncthreads();
    int tx = tid & 15, ty = tid >> 4;
    float acc[4][4] = {};
    #pragma unroll 8
    for (int kk = 0; kk < GG; kk++) {
        float aa[4], bb[4];
        #pragma unroll
        for (int i = 0; i < 4; i++) aa[i] = As[ty * 4 + i][kk];
        #pragma unroll
        for (int j = 0; j < 4; j++) bb[j] = Bs[tx * 4 + j][kk];
        #pragma unroll
        for (int i = 0; i < 4; i++)
            #pragma unroll
            for (int j = 0; j < 4; j++)
                acc[i][j] += aa[i] * bb[j];
    }
    float4 wb4 = *(const float4*)(w_b + bn + tx * 4);
    float wbv[4] = {wb4.x, wb4.y, wb4.z, wb4.w};
    #pragma unroll
    for (int i = 0; i < 4; i++) {
        float v[4];
        #pragma unroll
        for (int j = 0; j < 4; j++) v[j] = __expf(acc[i][j] + wbv[j]);
        *(float4*)(eb + (size_t)(bm + ty * 4 + i) * KDIM + bn + tx * 4) =
            make_float4(v[0], v[1], v[2], v[3]);
    }
}

// ---------------------------------------------------------------------------
// Kernel 5a (chunkA1): LDS-staged r/k/e; 2-way-parallel cumsum; r~,k~ in place;
// M = (k~ * Dtot)^T v; Dtot out; u fused.
// ---------------------------------------------------------------------------
__global__ __launch_bounds__(256) void k_chunkA1(
    const float* __restrict__ eb, float* __restrict__ rb,
    float* __restrict__ kb, const float* __restrict__ vb,
    const float* __restrict__ bonus, float* __restrict__ ub,
    float* __restrict__ Mb, float* __restrict__ Db)
{
    int bh = blockIdx.x;       // b*NH + h (h fast)
    int ck = blockIdx.y;       // 0..31
    int h = bh & 3, b = bh >> 2;
    int tok0 = b * TT + ck * CK;
    int tid = threadIdx.x;
    __shared__ float Ls[CK][128];
    __shared__ float rs[CK][129];
    __shared__ float kt[CK][129];
    __shared__ float vsm[CK][68];
    __shared__ float Dts[128];
    __shared__ float up[CK][8];
    #pragma unroll
    for (int i = 0; i < 16; i++) {
        int idx = i * 256 + tid;
        int t = idx >> 7, c = idx & 127;
        size_t g = (size_t)(tok0 + t) * KDIM + h * DKH + c;
        Ls[t][c] = eb[g];
        rs[t][c] = rb[g];
        kt[t][c] = kb[g];
    }
    __syncthreads();
    {
        int c = tid & 127, hf = tid >> 7;
        float run = 0.f;
        if (hf) {
            #pragma unroll
            for (int t = 0; t < 16; t++) run += Ls[t][c];
        }
        __syncthreads();    // prefix reads of Ls done before overwrites below
        float bc = bonus[h * DKH + c];
        #pragma unroll
        for (int tt2 = 0; tt2 < 16; tt2++) {
            int t = hf * 16 + tt2;
            size_t g = (size_t)(tok0 + t) * KDIM + h * DKH + c;
            float e = Ls[t][c];
            float rv = rs[t][c];
            float kv = kt[t][c];
            rb[g] = rv * __expf(-run);
            Ls[t][c] = rv * kv * bc;          // bonus partial
            run += e;
            float ks = kv * __expf(run);
            kt[t][c] = ks;
            kb[g] = ks;
        }
        if (hf) {
            float dt = __expf(-run);
            Dts[c] = dt;
            Db[(size_t)(bh * NCK + ck) * 128 + c] = dt;
        }
    }
    __syncthreads();
    {
        int t = tid >> 3, seg = tid & 7;
        float s = 0.f;
        #pragma unroll
        for (int q = 0; q < 16; q++) s += Ls[t][seg * 16 + q];
        up[t][seg] = s;
    }
    __syncthreads();
    if (tid < CK) {
        float s = 0.f;
        #pragma unroll
        for (int q = 0; q < 8; q++) s += up[tid][q];
        ub[(size_t)(tok0 + tid) * NHD + h] = s;
    }
    for (int jb = 0; jb < 4; jb++) {
        {
            int j = tid & 63, r0 = tid >> 6;
            #pragma unroll
            for (int i = 0; i < 8; i++) {
                int s = r0 + 4 * i;
                vsm[s][j] = vb[(size_t)(tok0 + s) * VDIM + h * DVH + jb * 64 + j];
            }
        }
        __syncthreads();
        {
            int kk0 = (tid >> 3) * 4;
            int j0 = (tid & 7) * 8;
            float m[4][8] = {};
            for (int s = 0; s < CK; s++) {
                float4 kv = *(const float4*)&kt[s][kk0];
                float4 v0 = *(const float4*)&vsm[s][j0];
                float4 v1 = *(const float4*)&vsm[s][j0 + 4];
                float ka[4] = {kv.x, kv.y, kv.z, kv.w};
                float va[8] = {v0.x, v0.y, v0.z, v0.w, v1.x, v1.y, v1.z, v1.w};
                #pragma unroll
                for (int i = 0; i < 4; i++)
                    #pragma unroll
                    for (int jj = 0; jj < 8; jj++)
                        m[i][jj] += ka[i] * va[jj];
            }
            #pragma unroll
            for (int i = 0; i < 4; i++) {
                float d = Dts[kk0 + i];
                size_t mb = ((size_t)(bh * NCK + ck) * 128 + kk0 + i) * DVH + jb * 64 + j0;
                *(float4*)(Mb + mb)     = make_float4(m[i][0] * d, m[i][1] * d, m[i][2] * d, m[i][3] * d);
                *(float4*)(Mb + mb + 4) = make_float4(m[i][4] * d, m[i][5] * d, m[i][6] * d, m[i][7] * d);
            }
        }
        __syncthreads();
    }
}

// ---------------------------------------------------------------------------
// Kernel 5b (chunkB): sequential over chunks with register prefetch.
// Coalesced mapping: thread = (k-row via wave id, float4 of j via lane).
// ---------------------------------------------------------------------------
__global__ __launch_bounds__(256) void k_chunkB(
    float* __restrict__ MS, const float* __restrict__ Db)
{
    int bh = blockIdx.x;
    int ks = blockIdx.y;               // 0..31 -> 4-row k group
    int tid = threadIdx.x;
    int k = ks * 4 + (tid >> 6);       // wave-uniform row
    int j0 = (tid & 63) * 4;           // lane-consecutive float4
    float4 S = make_float4(0.f, 0.f, 0.f, 0.f);
    float4 m; float d;
    {
        size_t kb0 = (size_t)(bh * NCK) * 128 + k;
        m = *(const float4*)(MS + kb0 * DVH + j0);
        d = Db[kb0];
    }
    for (int c = 0; c < NCK; c++) {
        size_t kbc = (size_t)(bh * NCK + c) * 128 + k;
        float4 mc = m; float dc = d;
        if (c + 1 < NCK) {
            size_t kbn = (size_t)(bh * NCK + c + 1) * 128 + k;
            m = *(const float4*)(MS + kbn * DVH + j0);
            d = Db[kbn];
        }
        *(float4*)(MS + kbc * DVH + j0) = S;
        S.x = S.x * dc + mc.x;
        S.y = S.y * dc + mc.y;
        S.z = S.z * dc + mc.z;
        S.w = S.w * dc + mc.w;
    }
}

// ---------------------------------------------------------------------------
// Kernel 5c (chunkCG v3, 1024 threads): P = mask(r~ k~^T, diag=u);
// o = P@v + r~@S (f32 regs); groupnorm; silu(g) gate; y f32 IN PLACE over v.
// S staged through LDS in 16-row tiles (each S byte crosses L2 once).
// ---------------------------------------------------------------------------
__global__ __launch_bounds__(1024) void k_chunkCG(
    const float* __restrict__ rb, const float* __restrict__ kb,
    float* __restrict__ vb, const float* __restrict__ ub,
    const float* __restrict__ Sb, const float* __restrict__ gb_,
    const float* __restrict__ gnw, const float* __restrict__ gnb)
{
    int bh = blockIdx.x, ck = blockIdx.y;
    int h = bh & 3, b = bh >> 2;
    int tok0 = b * TT + ck * CK;
    int tid = threadIdx.x;
    __shared__ float rt[CK][128];
    __shared__ float kt[CK][129];
    __shared__ float Ps[CK][33];
    __shared__ float stg[2][16][260];   // v staging (both halves), then S tiles in stg[0]
    #pragma unroll
    for (int i = 0; i < 4; i++) {
        int idx = i * 1024 + tid;
        int t = idx >> 7, c = idx & 127;
        size_t g = (size_t)(tok0 + t) * KDIM + h * DKH + c;
        rt[t][c] = rb[g];
        kt[t][c] = kb[g];
    }
    // stage v [32][256]
    {
        int r = tid >> 5, c0 = (tid & 31) * 8;
        const float* vp = vb + (size_t)(tok0 + r) * VDIM + h * DVH + c0;
        float4 a = *(const float4*)vp;
        float4 b2 = *(const float4*)(vp + 4);
        *(float4*)&stg[r >> 4][r & 15][c0]     = a;
        *(float4*)&stg[r >> 4][r & 15][c0 + 4] = b2;
    }
    __syncthreads();
    // P: 1 entry per thread
    {
        int t = tid >> 5, s = tid & 31;
        float a0 = 0.f;
        for (int k4 = 0; k4 < 128; k4 += 4) {
            float4 a = *(const float4*)&rt[t][k4];
            float4 b0 = *(const float4*)&kt[s][k4];
            a0 += a.x * b0.x + a.y * b0.y + a.z * b0.z + a.w * b0.w;
        }
        float u0 = ub[(size_t)(tok0 + t) * NHD + h];
        Ps[t][s] = (s < t) ? a0 : (s == t ? u0 : 0.f);
    }
    __syncthreads();
    int t0 = (tid >> 6) * 2;           // wave owns tokens t0, t0+1
    int c4 = (tid & 63) * 4;           // 64 lanes x 4 cols = full 256-col row
    float acc[2][4] = {};
    // intra-chunk: P @ v (from LDS)
    for (int s = 0; s < CK; s++) {
        float4 v0 = *(const float4*)&stg[s >> 4][s & 15][c4];
        float p0 = Ps[t0][s], p1 = Ps[t0 + 1][s];
        acc[0][0] += p0 * v0.x; acc[0][1] += p0 * v0.y;
        acc[0][2] += p0 * v0.z; acc[0][3] += p0 * v0.w;
        acc[1][0] += p1 * v0.x; acc[1][1] += p1 * v0.y;
        acc[1][2] += p1 * v0.z; acc[1][3] += p1 * v0.w;
    }
    // inter-chunk: r~ @ S, S tiled through LDS (each S byte read once from L2)
    size_t sbase = (size_t)(bh * NCK + ck) * 128 * DVH;
    int srow = tid >> 6;               // 0..15
    int scol = (tid & 63) * 4;
    float4 rg = *(const float4*)(Sb + sbase + (size_t)srow * DVH + scol);
    for (int tt = 0; tt < 8; tt++) {
        __syncthreads();               // prev tile (or v phase) reads complete
        *(float4*)&stg[0][srow][scol] = rg;
        if (tt < 7)
            rg = *(const float4*)(Sb + sbase + (size_t)((tt + 1) * 16 + srow) * DVH + scol);
        __syncthreads();               // tile staged
        #pragma unroll
        for (int q = 0; q < 16; q++) {
            int kk = tt * 16 + q;
            float4 s4 = *(const float4*)&stg[0][q][c4];
            float a0 = rt[t0][kk], a1 = rt[t0 + 1][kk];
            acc[0][0] += a0 * s4.x; acc[0][1] += a0 * s4.y;
            acc[0][2] += a0 * s4.z; acc[0][3] += a0 * s4.w;
            acc[1][0] += a1 * s4.x; acc[1][1] += a1 * s4.y;
            acc[1][2] += a1 * s4.z; acc[1][3] += a1 * s4.w;
        }
    }
    // groupnorm + affine + silu(g) gate, y f32 in place over v
    int cbase = h * DVH + c4;
    float4 gwA = *(const float4*)(gnw + cbase);
    float4 gbA = *(const float4*)(gnb + cbase);
    float gwv[4] = {gwA.x, gwA.y, gwA.z, gwA.w};
    float gbv[4] = {gbA.x, gbA.y, gbA.z, gbA.w};
    #pragma unroll
    for (int i = 0; i < 2; i++) {
        float sum = 0.f, sq = 0.f;
        #pragma unroll
        for (int jj = 0; jj < 4; jj++) {
            sum += acc[i][jj];
            sq  += acc[i][jj] * acc[i][jj];
        }
        #pragma unroll
        for (int m = 1; m < 64; m <<= 1) {
            sum += __shfl_xor(sum, m);
            sq  += __shfl_xor(sq, m);
        }
        float mean = sum * (1.f / DVH);
        float var = sq * (1.f / DVH) - mean * mean;
        float inv = rsqrtf(var + 1e-5f);
        size_t mrow = (size_t)(tok0 + t0 + i) * VDIM + cbase;
        float4 gA = *(const float4*)(gb_ + mrow);
        float gv[4] = {gA.x, gA.y, gA.z, gA.w};
        float o4[4];
        #pragma unroll
        for (int jj = 0; jj < 4; jj++) {
            float gg = gv[jj];
            float sig = 1.f / (1.f + __expf(-gg));
            o4[jj] = ((acc[i][jj] - mean) * inv * gwv[jj] + gbv[jj]) * (gg * sig);
        }
        *(float4*)(vb + mrow) = make_float4(o4[0], o4[1], o4[2], o4[3]);
    }
}

// ---------------------------------------------------------------------------
// Kernel 6: output GEMM, split precision. 64x128 tile. B-side staged via
// global_load_lds width=16 into LINEAR LDS [128][32] (512 chunks: each wave
// stages 2x64 chunks per buffer); A reg-staged (f2u hi/lo) into 40-pad LDS.
// ---------------------------------------------------------------------------
__global__ __launch_bounds__(256) void k_gemm_out(
    const float* __restrict__ A, const bf16* __restrict__ Bh,
    const bf16* __restrict__ Bl, float* __restrict__ C, int M, int N, int K)
{
    __shared__ unsigned short Ah[64 * 40];
    __shared__ unsigned short Al[64 * 40];
    __shared__ unsigned short Bhs[128 * 32];
    __shared__ unsigned short Bls[128 * 32];
    int tid = threadIdx.x;
    int bm = blockIdx.x * 64, bn = blockIdx.y * 128;
    int lane = tid & 63, w = tid >> 6;
    int wr = w >> 1, wc = w & 1;
    const unsigned short* Bh16 = (const unsigned short*)Bh;
    const unsigned short* Bl16 = (const unsigned short*)Bl;
    f32x4 acc[2][4];
    #pragma unroll
    for (int i = 0; i < 2; i++)
        #pragma unroll
        for (int j = 0; j < 4; j++)
            acc[i][j] = (f32x4){0.f, 0.f, 0.f, 0.f};
    int arow = tid >> 2, acol = (tid & 3) * 8;     // A: 64x32 f32, 8 per thread
    int fr = lane & 15, kb = (lane >> 4) * 8;
    int c0w = w * 128;
    for (int k0 = 0; k0 < K; k0 += 32) {
        float4 t4a = *(const float4*)(A + (size_t)(bm + arow) * K + k0 + acol);
        float4 t4b = *(const float4*)(A + (size_t)(bm + arow) * K + k0 + acol + 4);
        __syncthreads();                   // prev iteration frag reads complete
        #pragma unroll
        for (int q = 0; q < 2; q++) {
            int cb = c0w + q * 64;         // wave-uniform
            int c = cb + lane;
            int row = c >> 2, co = (c & 3) * 8;
            const unsigned short* gh2 = Bh16 + (size_t)(bn + row) * K + k0 + co;
            const unsigned short* gl2 = Bl16 + (size_t)(bn + row) * K + k0 + co;
            __builtin_amdgcn_global_load_lds(
                (const __attribute__((address_space(1))) void*)gh2,
                (__attribute__((address_space(3))) void*)(Bhs + cb * 8), 16, 0, 0);
            __builtin_amdgcn_global_load_lds(
                (const __attribute__((address_space(1))) void*)gl2,
                (__attribute__((address_space(3))) void*)(Bls + cb * 8), 16, 0, 0);
        }
        float av[8] = {t4a.x, t4a.y, t4a.z, t4a.w, t4b.x, t4b.y, t4b.z, t4b.w};
        alignas(16) unsigned short th[8], tl[8];
        #pragma unroll
        for (int q = 0; q < 8; q++) {
            unsigned short hu = f2u(av[q]);
            th[q] = hu;
            tl[q] = f2u(av[q] - u2f(hu));
        }
        *(uint4*)(Ah + arow * 40 + acol) = *(const uint4*)&th[0];
        *(uint4*)(Al + arow * 40 + acol) = *(const uint4*)&tl[0];
        __syncthreads();                   // gload_lds + A writes complete
        bf16x8 afh[2], afl[2], bfh[4], bfl[4];
        #pragma unroll
        for (int i = 0; i < 2; i++) {
            afh[i] = *(const bf16x8*)(Ah + (wr * 32 + i * 16 + fr) * 40 + kb);
            afl[i] = *(const bf16x8*)(Al + (wr * 32 + i * 16 + fr) * 40 + kb);
        }
        #pragma unroll
        for (int j = 0; j < 4; j++) {
            bfh[j] = *(const bf16x8*)(Bhs + (wc * 64 + j * 16 + fr) * 32 + kb);
            bfl[j] = *(const bf16x8*)(Bls + (wc * 64 + j * 16 + fr) * 32 + kb);
        }
        #pragma unroll
        for (int i = 0; i < 2; i++)
            #pragma unroll
            for (int j = 0; j < 4; j++) {
                acc[i][j] = __builtin_amdgcn_mfma_f32_16x16x32_bf16(afh[i], bfh[j], acc[i][j], 0, 0, 0);
                acc[i][j] = __builtin_amdgcn_mfma_f32_16x16x32_bf16(afl[i], bfh[j], acc[i][j], 0, 0, 0);
                acc[i][j] = __builtin_amdgcn_mfma_f32_16x16x32_bf16(afh[i], bfl[j], acc[i][j], 0, 0, 0);
            }
    }
    int er = (lane >> 4) * 4, ec = lane & 15;
    #pragma unroll
    for (int i = 0; i < 2; i++) {
        int gr = bm + wr * 32 + i * 16 + er;
        #pragma unroll
        for (int j = 0; j < 4; j++) {
            int gc = bn + wc * 64 + j * 16 + ec;
            #pragma unroll
            for (int q = 0; q < 4; q++)
                C[(size_t)(gr + q) * N + gc] = acc[i][j][q];
        }
    }
}

// ---------------------------------------------------------------------------
extern "C" void kernel_launch(void* const* d_in, const int* in_sizes, int n_in,
                              void* d_out, int out_size, void* d_ws, size_t ws_size,
                              hipStream_t stream)
{
    const float* h        = (const float*)d_in[0];
    const float* x_mu     = (const float*)d_in[1];
    const float* xl_w1    = (const float*)d_in[2];
    const float* xl_w2    = (const float*)d_in[3];
    const float* xl_b2    = (const float*)d_in[4];
    const float* x_out_w  = (const float*)d_in[5];
    const float* x_bias   = (const float*)d_in[6];
    const float* r_w      = (const float*)d_in[7];
    const float* w_w1     = (const float*)d_in[8];
    const float* w_w2     = (const float*)d_in[9];
    const float* w_b      = (const float*)d_in[10];
    const float* k_w      = (const float*)d_in[11];
    const float* v_w      = (const float*)d_in[12];
    const float* g_w      = (const float*)d_in[13];
    const float* bonus    = (const float*)d_in[14];
    const float* gn_w     = (const float*)d_in[15];
    const float* gn_b     = (const float*)d_in[16];
    const float* o_w      = (const float*)d_in[17];
    float* out = (float*)d_out;

    // Workspace overlay: total 35,733,504 floats = 142.9 MB (proven size)
    float* ws = (float*)d_ws;
    bf16*  wbf  = (bf16*)ws;                       // 8,388,608 bf16 = 4,194,304 slots
    float* rbuf = ws + 4194304;                    // 2,097,152
    float* vbuf = ws + 6291456;                    // 4,194,304 (y f32 in place later)
    float* gbuf = ws + 10485760;                   // 4,194,304
    float* kbuf = ws + 14680064;                   // 2,097,152
    float* ebuf = ws + 16777216;                   // 2,097,152
    float* ubuf = ws + 18874368;                   // 16,384
    float* Dbuf = ws + 18890752;                   // 65,536
    float* BIG  = ws + 18956288;                   // 16,777,216 (X phase / Mbuf)

    // weight hi/lo (bf16 element offsets within wbf)
    bf16* rwb_h = wbf;                  // 524,288
    bf16* kwb_h = wbf + 524288;
    bf16* vwb_h = wbf + 1048576;        // 1,048,576
    bf16* gwb_h = wbf + 2097152;
    bf16* owb_h = wbf + 3145728;
    bf16* rwb_l = wbf + 4194304;
    bf16* kwb_l = wbf + 4718592;
    bf16* vwb_l = wbf + 5242880;
    bf16* gwb_l = wbf + 6291456;
    bf16* owb_l = wbf + 7340032;

    // X phase inside BIG (each bf16 X = 2,097,152 float slots)
    float* Xw = BIG;                           // f32 [0 .. 4,194,304)
    bf16*  Xr = (bf16*)(BIG + 4194304);
    bf16*  Xk = (bf16*)(BIG + 6291456);
    bf16*  Xv = (bf16*)(BIG + 8388608);
    bf16*  Xg = (bf16*)(BIG + 10485760);
    float* x1   = BIG + 12582912;              // 655,360  (dead after mix)
    float* t0bf = BIG + 13238272;              // 131,072  (dead after k_x1b)
    float* w1p  = BIG + 12582912;              // 2,097,152 (after x1/t0 dead; dead before Mbuf)
    float* Mbuf = BIG;                         // full 16,777,216 after X dead
    float* ybuf = vbuf;                        // y f32 in place over v

    // weight conversion (hi/lo pairs), single launch
    k_f2b2_all<<<2048, 256, 0, stream>>>(r_w, k_w, v_w, g_w, o_w,
                                         rwb_h, rwb_l, kwb_h, kwb_l,
                                         vwb_h, vwb_l, gwb_h, gwb_l,
                                         owb_h, owb_l);

    // x1 path: MFMA phase-1 + small phase-2
    k_x1mm<<<NTOK / 64, 256, 0, stream>>>(h, x_mu, xl_w1, t0bf);
    k_x1b<<<NTOK / 64, 256, 0, stream>>>(t0bf, xl_w2, xl_b2, x1);

    // mix: f32 w-slice + MFMA bf16 four-slice (xow LDS-staged)
    k_mixw<<<dim3(NTOK / 64, HH / 64), 256, 0, stream>>>(h, x1, x_out_w, x_bias, Xw);
    k_mix4<<<dim3(NTOK / 64, HH / 64), 256, 0, stream>>>(h, x1, x_out_w, x_bias,
                                                         Xr, Xk, Xv, Xg);

    // projections: ALL FOUR hi/lo MFMA GEMMs in one launch (128x128 tiles,
    // global_load_lds staging); split-K f32 w path
    k_gemm_hl4<<<dim3(NTOK / 128, VDIM / 128, 4), 256, 0, stream>>>(
        Xr, rwb_h, rwb_l, rbuf,
        Xk, kwb_h, kwb_l, kbuf,
        Xv, vwb_h, vwb_l, vbuf,
        Xg, gwb_h, gwb_l, gbuf, NTOK, HH);
    k_w1<<<dim3(NTOK / 64, WKS), 256, 0, stream>>>(Xw, w_w1, w1p);
    k_we<<<dim3(NTOK / 64, KDIM / 64), 256, 0, stream>>>(w1p, w_w2, w_b, ebuf);

    k_chunkA1<<<dim3(BB * NHD, NCK), 256, 0, stream>>>(ebuf, rbuf, kbuf, vbuf,
                                                       bonus, ubuf, Mbuf, Dbuf);
    k_chunkB<<<dim3(BB * NHD, NCK), 256, 0, stream>>>(Mbuf, Dbuf);
    k_chunkCG<<<dim3(BB * NHD, NCK), 1024, 0, stream>>>(rbuf, kbuf, vbuf, ubuf, Mbuf,
                                                        gbuf, gn_w, gn_b);

    k_gemm_out<<<dim3(NTOK / 64, HH / 128), 256, 0, stream>>>(ybuf, owb_h, owb_l, out, NTOK, HH, VDIM);
}

// Round 25
// 271.399 us; speedup vs baseline: 1.1173x; 1.0285x over previous
//
#include <hip/hip_runtime.h>
#include <hip/hip_bf16.h>
#include <math.h>

// Problem constants
static constexpr int BB = 4;
static constexpr int TT = 1024;
static constexpr int HH = 1024;
static constexpr int NHD = 4;
static constexpr int KDIM = 512;
static constexpr int VDIM = 1024;
static constexpr int DKH = 128;   // KD / NH
static constexpr int DVH = 256;   // VD / NH
static constexpr int RR = 32;
static constexpr int R5D = 160;
static constexpr int GG = 64;
static constexpr int NTOK = BB * TT;   // 4096
static constexpr int CK = 32;          // chunk length
static constexpr int NCK = TT / CK;    // 32 chunks per sequence
static constexpr int WKS = 8;          // split-K factor for the w1 gemm

typedef __bf16 bf16x8 __attribute__((ext_vector_type(8)));
typedef float f32x4 __attribute__((ext_vector_type(4)));
typedef __hip_bfloat16 bf16;

static __device__ inline unsigned short f2u(float v) {
    __hip_bfloat16 b = __float2bfloat16(v);
    unsigned short u; __builtin_memcpy(&u, &b, 2); return u;
}
static __device__ inline float u2f(unsigned short u) {
    __hip_bfloat16 b; __builtin_memcpy(&b, &u, 2); return __bfloat162float(b);
}

// ---------------------------------------------------------------------------
// Kernel 1 (k_x1f): blocks 0..63: fused x1 path (t0 via LDS, then x1 =
// tanh(t0 @ w2^T + b2)); blocks 64..2111: f2b2 weight conversion.
// Both paths proven correct in isolation (R20 k_x1, R22 k_pre).
// ---------------------------------------------------------------------------
__global__ __launch_bounds__(256) void k_x1f(
    const float* __restrict__ h, const float* __restrict__ mu,
    const float* __restrict__ w1, const float* __restrict__ w2,
    const float* __restrict__ b2, float* __restrict__ x1out,
    const float* __restrict__ r_w, const float* __restrict__ k_w,
    const float* __restrict__ v_w, const float* __restrict__ g_w,
    const float* __restrict__ o_w,
    bf16* __restrict__ rh, bf16* __restrict__ rl,
    bf16* __restrict__ kh, bf16* __restrict__ kl,
    bf16* __restrict__ vh, bf16* __restrict__ vl,
    bf16* __restrict__ gh, bf16* __restrict__ gl,
    bf16* __restrict__ oh, bf16* __restrict__ ol)
{
    __shared__ unsigned short Al[64][40];
    __shared__ unsigned short Bl[32][40];
    __shared__ float t0s[64][33];
    __shared__ float w2s[R5D * RR];
    __shared__ float b2s[R5D];
    int tid = threadIdx.x;
    if (blockIdx.x >= 64) {
        // ---- f2b2 path ----
        size_t g = ((size_t)(blockIdx.x - 64) * 256 + tid) * 8;
        const float* s; bf16 *hi, *lo; size_t off;
        if (g < 524288)       { s = r_w; hi = rh; lo = rl; off = g; }
        else if (g < 1048576) { s = k_w; hi = kh; lo = kl; off = g - 524288; }
        else if (g < 2097152) { s = v_w; hi = vh; lo = vl; off = g - 1048576; }
        else if (g < 3145728) { s = g_w; hi = gh; lo = gl; off = g - 2097152; }
        else                  { s = o_w; hi = oh; lo = ol; off = g - 3145728; }
        #pragma unroll
        for (int j = 0; j < 8; j++) {
            float v = s[off + j];
            bf16 hb = __float2bfloat16(v);
            hi[off + j] = hb;
            lo[off + j] = __float2bfloat16(v - __bfloat162float(hb));
        }
        return;
    }
    // ---- fused x1 path ----
    int m0 = blockIdx.x * 64;
    int lane = tid & 63, w = tid >> 6;
    f32x4 acc[2];
    acc[0] = (f32x4){0.f, 0.f, 0.f, 0.f};
    acc[1] = (f32x4){0.f, 0.f, 0.f, 0.f};
    int ar = tid >> 2, ac0 = (tid & 3) * 8;        // A stage: 64x32, 8 per thread
    int br = tid >> 3, bc0 = (tid & 7) * 4;        // B stage: 32x32, 4 per thread
    int fr = lane & 15, kb = lane >> 4;
    int mrow = m0 + ar;
    int trow = mrow & (TT - 1);
    const float* hp = h + (size_t)mrow * HH;
    for (int k0 = 0; k0 < HH; k0 += 32) {
        float av[8];
        #pragma unroll
        for (int j = 0; j < 8; j += 4) {
            float4 c4 = *(const float4*)(hp + k0 + ac0 + j);
            float4 p4 = make_float4(0.f, 0.f, 0.f, 0.f);
            if (trow > 0) p4 = *(const float4*)(hp + k0 + ac0 + j - HH);
            float4 m4 = *(const float4*)(mu + k0 + ac0 + j);
            av[j + 0] = c4.x + (p4.x - c4.x) * m4.x;
            av[j + 1] = c4.y + (p4.y - c4.y) * m4.y;
            av[j + 2] = c4.z + (p4.z - c4.z) * m4.z;
            av[j + 3] = c4.w + (p4.w - c4.w) * m4.w;
        }
        float4 b4 = *(const float4*)(w1 + (size_t)br * HH + k0 + bc0);
        __syncthreads();
        #pragma unroll
        for (int j = 0; j < 8; j++) Al[ar][ac0 + j] = f2u(av[j]);
        Bl[br][bc0 + 0] = f2u(b4.x); Bl[br][bc0 + 1] = f2u(b4.y);
        Bl[br][bc0 + 2] = f2u(b4.z); Bl[br][bc0 + 3] = f2u(b4.w);
        __syncthreads();
        bf16x8 af = *(const bf16x8*)(&Al[w * 16 + fr][kb * 8]);
        bf16x8 bf0 = *(const bf16x8*)(&Bl[fr][kb * 8]);
        bf16x8 bf1 = *(const bf16x8*)(&Bl[16 + fr][kb * 8]);
        acc[0] = __builtin_amdgcn_mfma_f32_16x16x32_bf16(af, bf0, acc[0], 0, 0, 0);
        acc[1] = __builtin_amdgcn_mfma_f32_16x16x32_bf16(af, bf1, acc[1], 0, 0, 0);
    }
    // stage w2/b2 (independent buffers, no hazard with Al/Bl)
    for (int i = tid; i < R5D * RR; i += 256) w2s[i] = w2[i];
    if (tid < R5D) b2s[tid] = b2[tid];
    // epilogue: t0 = tanh(acc) into LDS
    {
        int er = (lane >> 4) * 4, ec = lane & 15;
        #pragma unroll
        for (int j = 0; j < 2; j++) {
            #pragma unroll
            for (int q = 0; q < 4; q++) {
                t0s[w * 16 + er + q][j * 16 + ec] = tanhf(acc[j][q]);
            }
        }
    }
    __syncthreads();
    // phase 2: x1 = tanh(t0 @ w2^T + b2)
    int tt = tid & 63, cg = tid >> 6;
    float t0r[32];
    #pragma unroll
    for (int q = 0; q < 32; q++) t0r[q] = t0s[tt][q];
    float* xo = x1out + (size_t)(m0 + tt) * R5D + cg * 40;
    for (int c = 0; c < 40; c++) {
        const float* wr = w2s + (cg * 40 + c) * RR;
        float s = b2s[cg * 40 + c];
        #pragma unroll
        for (int q = 0; q < 32; q++) s += t0r[q] * wr[q];
        xo[c] = tanhf(s);
    }
}

// ---------------------------------------------------------------------------
// Kernel 2a (k_mixw): n=1 slice only (w path, f32 exact).
// ---------------------------------------------------------------------------
__global__ __launch_bounds__(256) void k_mixw(
    const float* __restrict__ h, const float* __restrict__ x1,
    const float* __restrict__ xow, const float* __restrict__ xb,
    float* __restrict__ xw)
{
    int m0 = blockIdx.x * 64;
    int h0 = blockIdx.y * 64;
    int tid = threadIdx.x;
    __shared__ float x1sT[32][68];
    __shared__ float xosT[32][68];
    int rr = tid & 63, cg = tid >> 6;    // cg = wave id, 8 cols each
    {
        const float* xp = x1 + (size_t)(m0 + rr) * R5D + 32 + cg * 8;
        const float* wp = xow + (size_t)(h0 + rr) * R5D + 32 + cg * 8;
        float4 a0 = *(const float4*)xp, a1 = *(const float4*)(xp + 4);
        float4 b0 = *(const float4*)wp, b1 = *(const float4*)(wp + 4);
        x1sT[cg * 8 + 0][rr] = a0.x; x1sT[cg * 8 + 1][rr] = a0.y;
        x1sT[cg * 8 + 2][rr] = a0.z; x1sT[cg * 8 + 3][rr] = a0.w;
        x1sT[cg * 8 + 4][rr] = a1.x; x1sT[cg * 8 + 5][rr] = a1.y;
        x1sT[cg * 8 + 6][rr] = a1.z; x1sT[cg * 8 + 7][rr] = a1.w;
        xosT[cg * 8 + 0][rr] = b0.x; xosT[cg * 8 + 1][rr] = b0.y;
        xosT[cg * 8 + 2][rr] = b0.z; xosT[cg * 8 + 3][rr] = b0.w;
        xosT[cg * 8 + 4][rr] = b1.x; xosT[cg * 8 + 5][rr] = b1.y;
        xosT[cg * 8 + 6][rr] = b1.z; xosT[cg * 8 + 7][rr] = b1.w;
    }
    int tx = tid & 15, ty = tid >> 4;
    float creg[4][4], dreg[4][4];
    #pragma unroll
    for (int i = 0; i < 4; i++) {
        int m = m0 + ty * 4 + i;
        int t = m & (TT - 1);
        const float* hp = h + (size_t)m * HH + h0 + tx * 4;
        float4 c4 = *(const float4*)hp;
        float4 p4 = make_float4(0.f, 0.f, 0.f, 0.f);
        if (t > 0) p4 = *(const float4*)(hp - HH);
        creg[i][0] = c4.x; dreg[i][0] = p4.x - c4.x;
        creg[i][1] = c4.y; dreg[i][1] = p4.y - c4.y;
        creg[i][2] = c4.z; dreg[i][2] = p4.z - c4.z;
        creg[i][3] = c4.w; dreg[i][3] = p4.w - c4.w;
    }
    __syncthreads();
    float acc[4][4] = {};
    #pragma unroll
    for (int r2 = 0; r2 < 32; r2++) {
        float4 a4 = *(const float4*)&x1sT[r2][ty * 4];
        float4 b4 = *(const float4*)&xosT[r2][tx * 4];
        float aa[4] = {a4.x, a4.y, a4.z, a4.w};
        float bb[4] = {b4.x, b4.y, b4.z, b4.w};
        #pragma unroll
        for (int i = 0; i < 4; i++)
            #pragma unroll
            for (int j = 0; j < 4; j++)
                acc[i][j] += aa[i] * bb[j];
    }
    float4 xb4 = *(const float4*)(xb + HH + h0 + tx * 4);   // n=1 row of x_bias
    float xbv[4] = {xb4.x, xb4.y, xb4.z, xb4.w};
    #pragma unroll
    for (int i = 0; i < 4; i++) {
        size_t idx = (size_t)(m0 + ty * 4 + i) * HH + h0 + tx * 4;
        float v[4];
        #pragma unroll
        for (int j = 0; j < 4; j++)
            v[j] = creg[i][j] + dreg[i][j] * (acc[i][j] + xbv[j]);
        *(float4*)(xw + idx) = make_float4(v[0], v[1], v[2], v[3]);
    }
}

// ---------------------------------------------------------------------------
// Kernel 2b (k_mix4): n in {0,2,3,4} via MFMA. B-side (xow) staged in LDS,
// compacted to the 4 used 32-col slots: xs[64][132].
// ---------------------------------------------------------------------------
__global__ __launch_bounds__(256) void k_mix4(
    const float* __restrict__ h, const float* __restrict__ x1,
    const float* __restrict__ xow, const float* __restrict__ xb,
    bf16* __restrict__ xr, bf16* __restrict__ xk,
    bf16* __restrict__ xv, bf16* __restrict__ xg)
{
    __shared__ float xs[64][132];      // slot s holds xow cols ns[s]*32..+31
    int m0 = blockIdx.x * 64;
    int h0 = blockIdx.y * 64;
    int tid = threadIdx.x;
    int lane = tid & 63, w = tid >> 6;
    int fr = lane & 15, kb = (lane >> 4) * 8;
    int er = (lane >> 4) * 4, ec = lane & 15;
    const int ns[4] = {0, 2, 3, 4};
    // stage xow tile: 64 rows x 4 slots x 32 cols = 2048 float4 groups
    #pragma unroll
    for (int it = 0; it < 8; it++) {
        int idx = it * 256 + tid;
        int row = idx >> 5;            // 0..63
        int cg = idx & 31;             // float4 col group
        int slot = cg >> 3, wi = (cg & 7) * 4;
        float4 v = *(const float4*)(xow + (size_t)(h0 + row) * R5D + ns[slot] * 32 + wi);
        *(float4*)&xs[row][slot * 32 + wi] = v;
    }
    float creg[4][4], dreg[4][4];
    #pragma unroll
    for (int q = 0; q < 4; q++) {
        int m = m0 + w * 16 + er + q;
        int t = m & (TT - 1);
        const float* hp = h + (size_t)m * HH;
        #pragma unroll
        for (int j = 0; j < 4; j++) {
            int hh = h0 + j * 16 + ec;
            float c = hp[hh];
            float p = (t > 0) ? hp[hh - HH] : 0.f;
            creg[q][j] = c;
            dreg[q][j] = p - c;
        }
    }
    __syncthreads();
    bf16* outs[4] = {xr, xk, xv, xg};
    #pragma unroll
    for (int ni = 0; ni < 4; ni++) {
        int n = ns[ni];
        const float* ap = x1 + (size_t)(m0 + w * 16 + fr) * R5D + n * 32 + kb;
        float4 a0 = *(const float4*)ap;
        float4 a1 = *(const float4*)(ap + 4);
        alignas(16) unsigned short ta[8];
        ta[0] = f2u(a0.x); ta[1] = f2u(a0.y); ta[2] = f2u(a0.z); ta[3] = f2u(a0.w);
        ta[4] = f2u(a1.x); ta[5] = f2u(a1.y); ta[6] = f2u(a1.z); ta[7] = f2u(a1.w);
        bf16x8 af = *(const bf16x8*)ta;
        f32x4 accj[4];
        #pragma unroll
        for (int j = 0; j < 4; j++) {
            const float* bp = &xs[j * 16 + fr][ni * 32 + kb];
            float4 b0 = *(const float4*)bp;
            float4 b1 = *(const float4*)(bp + 4);
            alignas(16) unsigned short tb[8];
            tb[0] = f2u(b0.x); tb[1] = f2u(b0.y); tb[2] = f2u(b0.z); tb[3] = f2u(b0.w);
            tb[4] = f2u(b1.x); tb[5] = f2u(b1.y); tb[6] = f2u(b1.z); tb[7] = f2u(b1.w);
            bf16x8 bf_ = *(const bf16x8*)tb;
            f32x4 z = (f32x4){0.f, 0.f, 0.f, 0.f};
            accj[j] = __builtin_amdgcn_mfma_f32_16x16x32_bf16(af, bf_, z, 0, 0, 0);
        }
        bf16* op = outs[ni];
        #pragma unroll
        for (int j = 0; j < 4; j++) {
            float xbv = xb[n * HH + h0 + j * 16 + ec];
            #pragma unroll
            for (int q = 0; q < 4; q++) {
                float val = creg[q][j] + dreg[q][j] * (accj[j][q] + xbv);
                op[(size_t)(m0 + w * 16 + er + q) * HH + h0 + j * 16 + ec] =
                    __float2bfloat16(val);
            }
        }
    }
}

// ---------------------------------------------------------------------------
// Kernel 3a (k_gemm_hl4): FOUR hi/lo GEMMs in one launch (z: 0=r,1=k N=512;
// 2=v,3=g N=1024). 128x128 tile. Staging via global_load_lds width=16 into
// LINEAR LDS [128][32] (wave-uniform dest + lane*16B). m97-proven structure.
// ---------------------------------------------------------------------------
__global__ __launch_bounds__(256) void k_gemm_hl4(
    const bf16* __restrict__ A0, const bf16* __restrict__ Bh0,
    const bf16* __restrict__ Bl0, float* __restrict__ C0,
    const bf16* __restrict__ A1, const bf16* __restrict__ Bh1,
    const bf16* __restrict__ Bl1, float* __restrict__ C1,
    const bf16* __restrict__ A2, const bf16* __restrict__ Bh2,
    const bf16* __restrict__ Bl2, float* __restrict__ C2,
    const bf16* __restrict__ A3, const bf16* __restrict__ Bh3,
    const bf16* __restrict__ Bl3, float* __restrict__ C3,
    int M, int K)
{
    int z = blockIdx.z;
    const bf16* A;
    const bf16* Bh;
    const bf16* Bl;
    float* C;
    int N;
    if (z == 0)      { A = A0; Bh = Bh0; Bl = Bl0; C = C0; N = KDIM; }
    else if (z == 1) { A = A1; Bh = Bh1; Bl = Bl1; C = C1; N = KDIM; }
    else if (z == 2) { A = A2; Bh = Bh2; Bl = Bl2; C = C2; N = VDIM; }
    else             { A = A3; Bh = Bh3; Bl = Bl3; C = C3; N = VDIM; }
    int bn = blockIdx.y * 128;
    if (bn >= N) return;
    __shared__ unsigned short As[128 * 32];
    __shared__ unsigned short Bhs[128 * 32];
    __shared__ unsigned short Bls[128 * 32];
    int tid = threadIdx.x;
    int bm = blockIdx.x * 128;
    int lane = tid & 63, w = tid >> 6;
    int wr = w >> 1, wc = w & 1;
    const unsigned short* A16 = (const unsigned short*)A;
    const unsigned short* Bh16 = (const unsigned short*)Bh;
    const unsigned short* Bl16 = (const unsigned short*)Bl;
    f32x4 acc[4][4];
    #pragma unroll
    for (int i = 0; i < 4; i++)
        #pragma unroll
        for (int j = 0; j < 4; j++)
            acc[i][j] = (f32x4){0.f, 0.f, 0.f, 0.f};
    int fr = lane & 15, kb = (lane >> 4) * 8;
    // chunk mapping: chunk c (16B) covers row c>>2, col (c&3)*8 shorts.
    int c0w = w * 128;
    for (int k0 = 0; k0 < K; k0 += 32) {
        #pragma unroll
        for (int q = 0; q < 2; q++) {
            int cb = c0w + q * 64;            // wave-uniform
            int c = cb + lane;
            int row = c >> 2, co = (c & 3) * 8;
            const unsigned short* ga = A16 + (size_t)(bm + row) * K + k0 + co;
            const unsigned short* gh2 = Bh16 + (size_t)(bn + row) * K + k0 + co;
            const unsigned short* gl2 = Bl16 + (size_t)(bn + row) * K + k0 + co;
            __builtin_amdgcn_global_load_lds(
                (const __attribute__((address_space(1))) void*)ga,
                (__attribute__((address_space(3))) void*)(As + cb * 8), 16, 0, 0);
            __builtin_amdgcn_global_load_lds(
                (const __attribute__((address_space(1))) void*)gh2,
                (__attribute__((address_space(3))) void*)(Bhs + cb * 8), 16, 0, 0);
            __builtin_amdgcn_global_load_lds(
                (const __attribute__((address_space(1))) void*)gl2,
                (__attribute__((address_space(3))) void*)(Bls + cb * 8), 16, 0, 0);
        }
        __syncthreads();
        bf16x8 af[4], bfh[4], bfl[4];
        #pragma unroll
        for (int i = 0; i < 4; i++) {
            af[i]  = *(const bf16x8*)(As + (wr * 64 + i * 16 + fr) * 32 + kb);
            bfh[i] = *(const bf16x8*)(Bhs + (wc * 64 + i * 16 + fr) * 32 + kb);
            bfl[i] = *(const bf16x8*)(Bls + (wc * 64 + i * 16 + fr) * 32 + kb);
        }
        #pragma unroll
        for (int i = 0; i < 4; i++)
            #pragma unroll
            for (int j = 0; j < 4; j++) {
                acc[i][j] = __builtin_amdgcn_mfma_f32_16x16x32_bf16(af[i], bfh[j], acc[i][j], 0, 0, 0);
                acc[i][j] = __builtin_amdgcn_mfma_f32_16x16x32_bf16(af[i], bfl[j], acc[i][j], 0, 0, 0);
            }
        __syncthreads();
    }
    int er = (lane >> 4) * 4, ec = lane & 15;
    #pragma unroll
    for (int i = 0; i < 4; i++) {
        int gr = bm + wr * 64 + i * 16 + er;
        #pragma unroll
        for (int j = 0; j < 4; j++) {
            int gc = bn + wc * 64 + j * 16 + ec;
            #pragma unroll
            for (int q = 0; q < 4; q++)
                C[(size_t)(gr + q) * N + gc] = acc[i][j][q];
        }
    }
}

// ---------------------------------------------------------------------------
// Kernel 3b (k_w1): split-K partial GEMM for the w path.
// ---------------------------------------------------------------------------
__global__ __launch_bounds__(256) void k_w1(
    const float* __restrict__ A, const float* __restrict__ Bm,
    float* __restrict__ P)
{
    __shared__ float As[16][68];
    __shared__ float Bs[16][68];
    int tid = threadIdx.x;
    int bm = blockIdx.x * 64;
    int ks = blockIdx.y;
    int kbase = ks * (HH / WKS);       // 128-wide K slice
    int tx = tid & 15, ty = tid >> 4;
    int lr = tid >> 2;
    int lk = (tid & 3) * 4;
    float acc[4][4] = {};
    for (int k0 = 0; k0 < HH / WKS; k0 += 16) {
        float4 av = *(const float4*)(A + (size_t)(bm + lr) * HH + kbase + k0 + lk);
        float4 bv = *(const float4*)(Bm + (size_t)lr * HH + kbase + k0 + lk);
        As[lk + 0][lr] = av.x; As[lk + 1][lr] = av.y;
        As[lk + 2][lr] = av.z; As[lk + 3][lr] = av.w;
        Bs[lk + 0][lr] = bv.x; Bs[lk + 1][lr] = bv.y;
        Bs[lk + 2][lr] = bv.z; Bs[lk + 3][lr] = bv.w;
        __syncthreads();
        #pragma unroll
        for (int kk = 0; kk < 16; kk++) {
            float4 a4 = *(const float4*)&As[kk][ty * 4];
            float4 b4 = *(const float4*)&Bs[kk][tx * 4];
            float aa[4] = {a4.x, a4.y, a4.z, a4.w};
            float bb[4] = {b4.x, b4.y, b4.z, b4.w};
            #pragma unroll
            for (int i = 0; i < 4; i++)
                #pragma unroll
                for (int j = 0; j < 4; j++)
                    acc[i][j] += aa[i] * bb[j];
        }
        __syncthreads();
    }
    #pragma unroll
    for (int i = 0; i < 4; i++) {
        size_t row = (size_t)ks * NTOK + bm + ty * 4 + i;
        *(float4*)(P + row * GG + tx * 4) =
            make_float4(acc[i][0], acc[i][1], acc[i][2], acc[i][3]);
    }
}

// ---------------------------------------------------------------------------
// Kernel 3c (k_we): e = exp( tanh(sum_ks P) @ w_w2^T + w_b ).
// ---------------------------------------------------------------------------
__global__ __launch_bounds__(256) void k_we(
    const float* __restrict__ P, const float* __restrict__ w_w2,
    const float* __restrict__ w_b, float* __restrict__ eb)
{
    __shared__ float As[64][65];
    __shared__ float Bs[64][65];
    int tid = threadIdx.x;
    int bm = blockIdx.x * 64, bn = blockIdx.y * 64;
    {
        int r = tid >> 2, c0 = (tid & 3) * 16;
        float s[16];
        #pragma unroll
        for (int j = 0; j < 16; j++) s[j] = 0.f;
        for (int ks = 0; ks < WKS; ks++) {
            const float* pp = P + ((size_t)ks * NTOK + bm + r) * GG + c0;
            #pragma unroll
            for (int j = 0; j < 16; j += 4) {
                float4 v = *(const float4*)(pp + j);
                s[j + 0] += v.x; s[j + 1] += v.y; s[j + 2] += v.z; s[j + 3] += v.w;
            }
        }
        #pragma unroll
        for (int j = 0; j < 16; j++) As[r][c0 + j] = tanhf(s[j]);
        const float* bp = w_w2 + (size_t)(bn + r) * GG + c0;
        #pragma unroll
        for (int j = 0; j < 16; j += 4) {
            float4 v = *(const float4*)(bp + j);
            Bs[r][c0 + j + 0] = v.x; Bs[r][c0 + j + 1] = v.y;
            Bs[r][c0 + j + 2] = v.z; Bs[r][c0 + j + 3] = v.w;
        }
    }
    __syncthreads();
    int tx = tid & 15, ty = tid >> 4;
    float acc[4][4] = {};
    #pragma unroll 8
    for (int kk = 0; kk < GG; kk++) {
        float aa[4], bb[4];
        #pragma unroll
        for (int i = 0; i < 4; i++) aa[i] = As[ty * 4 + i][kk];
        #pragma unroll
        for (int j = 0; j < 4; j++) bb[j] = Bs[tx * 4 + j][kk];
        #pragma unroll
        for (int i = 0; i < 4; i++)
            #pragma unroll
            for (int j = 0; j < 4; j++)
                acc[i][j] += aa[i] * bb[j];
    }
    float4 wb4 = *(const float4*)(w_b + bn + tx * 4);
    float wbv[4] = {wb4.x, wb4.y, wb4.z, wb4.w};
    #pragma unroll
    for (int i = 0; i < 4; i++) {
        float v[4];
        #pragma unroll
        for (int j = 0; j < 4; j++) v[j] = __expf(acc[i][j] + wbv[j]);
        *(float4*)(eb + (size_t)(bm + ty * 4 + i) * KDIM + bn + tx * 4) =
            make_float4(v[0], v[1], v[2], v[3]);
    }
}

// ---------------------------------------------------------------------------
// Kernel 5a (chunkA1): LDS-staged r/k/e; 2-way-parallel cumsum; r~,k~ in place;
// M = (k~ * Dtot)^T v; Dtot out; u fused.
// ---------------------------------------------------------------------------
__global__ __launch_bounds__(256) void k_chunkA1(
    const float* __restrict__ eb, float* __restrict__ rb,
    float* __restrict__ kb, const float* __restrict__ vb,
    const float* __restrict__ bonus, float* __restrict__ ub,
    float* __restrict__ Mb, float* __restrict__ Db)
{
    int bh = blockIdx.x;       // b*NH + h (h fast)
    int ck = blockIdx.y;       // 0..31
    int h = bh & 3, b = bh >> 2;
    int tok0 = b * TT + ck * CK;
    int tid = threadIdx.x;
    __shared__ float Ls[CK][128];
    __shared__ float rs[CK][129];
    __shared__ float kt[CK][129];
    __shared__ float vsm[CK][68];
    __shared__ float Dts[128];
    __shared__ float up[CK][8];
    #pragma unroll
    for (int i = 0; i < 16; i++) {
        int idx = i * 256 + tid;
        int t = idx >> 7, c = idx & 127;
        size_t g = (size_t)(tok0 + t) * KDIM + h * DKH + c;
        Ls[t][c] = eb[g];
        rs[t][c] = rb[g];
        kt[t][c] = kb[g];
    }
    __syncthreads();
    {
        int c = tid & 127, hf = tid >> 7;
        float run = 0.f;
        if (hf) {
            #pragma unroll
            for (int t = 0; t < 16; t++) run += Ls[t][c];
        }
        __syncthreads();    // prefix reads of Ls done before overwrites below
        float bc = bonus[h * DKH + c];
        #pragma unroll
        for (int tt2 = 0; tt2 < 16; tt2++) {
            int t = hf * 16 + tt2;
            size_t g = (size_t)(tok0 + t) * KDIM + h * DKH + c;
            float e = Ls[t][c];
            float rv = rs[t][c];
            float kv = kt[t][c];
            rb[g] = rv * __expf(-run);
            Ls[t][c] = rv * kv * bc;          // bonus partial
            run += e;
            float ks = kv * __expf(run);
            kt[t][c] = ks;
            kb[g] = ks;
        }
        if (hf) {
            float dt = __expf(-run);
            Dts[c] = dt;
            Db[(size_t)(bh * NCK + ck) * 128 + c] = dt;
        }
    }
    __syncthreads();
    {
        int t = tid >> 3, seg = tid & 7;
        float s = 0.f;
        #pragma unroll
        for (int q = 0; q < 16; q++) s += Ls[t][seg * 16 + q];
        up[t][seg] = s;
    }
    __syncthreads();
    if (tid < CK) {
        float s = 0.f;
        #pragma unroll
        for (int q = 0; q < 8; q++) s += up[tid][q];
        ub[(size_t)(tok0 + tid) * NHD + h] = s;
    }
    for (int jb = 0; jb < 4; jb++) {
        {
            int j = tid & 63, r0 = tid >> 6;
            #pragma unroll
            for (int i = 0; i < 8; i++) {
                int s = r0 + 4 * i;
                vsm[s][j] = vb[(size_t)(tok0 + s) * VDIM + h * DVH + jb * 64 + j];
            }
        }
        __syncthreads();
        {
            int kk0 = (tid >> 3) * 4;
            int j0 = (tid & 7) * 8;
            float m[4][8] = {};
            for (int s = 0; s < CK; s++) {
                float4 kv = *(const float4*)&kt[s][kk0];
                float4 v0 = *(const float4*)&vsm[s][j0];
                float4 v1 = *(const float4*)&vsm[s][j0 + 4];
                float ka[4] = {kv.x, kv.y, kv.z, kv.w};
                float va[8] = {v0.x, v0.y, v0.z, v0.w, v1.x, v1.y, v1.z, v1.w};
                #pragma unroll
                for (int i = 0; i < 4; i++)
                    #pragma unroll
                    for (int jj = 0; jj < 8; jj++)
                        m[i][jj] += ka[i] * va[jj];
            }
            #pragma unroll
            for (int i = 0; i < 4; i++) {
                float d = Dts[kk0 + i];
                size_t mb = ((size_t)(bh * NCK + ck) * 128 + kk0 + i) * DVH + jb * 64 + j0;
                *(float4*)(Mb + mb)     = make_float4(m[i][0] * d, m[i][1] * d, m[i][2] * d, m[i][3] * d);
                *(float4*)(Mb + mb + 4) = make_float4(m[i][4] * d, m[i][5] * d, m[i][6] * d, m[i][7] * d);
            }
        }
        __syncthreads();
    }
}

// ---------------------------------------------------------------------------
// Kernel 5b (chunkB): sequential over chunks with register prefetch.
// Coalesced mapping: thread = (k-row via wave id, float4 of j via lane).
// ---------------------------------------------------------------------------
__global__ __launch_bounds__(256) void k_chunkB(
    float* __restrict__ MS, const float* __restrict__ Db)
{
    int bh = blockIdx.x;
    int ks = blockIdx.y;               // 0..31 -> 4-row k group
    int tid = threadIdx.x;
    int k = ks * 4 + (tid >> 6);       // wave-uniform row
    int j0 = (tid & 63) * 4;           // lane-consecutive float4
    float4 S = make_float4(0.f, 0.f, 0.f, 0.f);
    float4 m; float d;
    {
        size_t kb0 = (size_t)(bh * NCK) * 128 + k;
        m = *(const float4*)(MS + kb0 * DVH + j0);
        d = Db[kb0];
    }
    for (int c = 0; c < NCK; c++) {
        size_t kbc = (size_t)(bh * NCK + c) * 128 + k;
        float4 mc = m; float dc = d;
        if (c + 1 < NCK) {
            size_t kbn = (size_t)(bh * NCK + c + 1) * 128 + k;
            m = *(const float4*)(MS + kbn * DVH + j0);
            d = Db[kbn];
        }
        *(float4*)(MS + kbc * DVH + j0) = S;
        S.x = S.x * dc + mc.x;
        S.y = S.y * dc + mc.y;
        S.z = S.z * dc + mc.z;
        S.w = S.w * dc + mc.w;
    }
}

// ---------------------------------------------------------------------------
// Kernel 5c (chunkCG v3, 1024 threads): P = mask(r~ k~^T, diag=u);
// o = P@v + r~@S (f32 regs); groupnorm; silu(g) gate; y f32 IN PLACE over v.
// S staged through LDS in 16-row tiles (each S byte crosses L2 once).
// ---------------------------------------------------------------------------
__global__ __launch_bounds__(1024) void k_chunkCG(
    const float* __restrict__ rb, const float* __restrict__ kb,
    float* __restrict__ vb, const float* __restrict__ ub,
    const float* __restrict__ Sb, const float* __restrict__ gb_,
    const float* __restrict__ gnw, const float* __restrict__ gnb)
{
    int bh = blockIdx.x, ck = blockIdx.y;
    int h = bh & 3, b = bh >> 2;
    int tok0 = b * TT + ck * CK;
    int tid = threadIdx.x;
    __shared__ float rt[CK][128];
    __shared__ float kt[CK][129];
    __shared__ float Ps[CK][33];
    __shared__ float stg[2][16][260];   // v staging (both halves), then S tiles in stg[0]
    #pragma unroll
    for (int i = 0; i < 4; i++) {
        int idx = i * 1024 + tid;
        int t = idx >> 7, c = idx & 127;
        size_t g = (size_t)(tok0 + t) * KDIM + h * DKH + c;
        rt[t][c] = rb[g];
        kt[t][c] = kb[g];
    }
    // stage v [32][256]
    {
        int r = tid >> 5, c0 = (tid & 31) * 8;
        const float* vp = vb + (size_t)(tok0 + r) * VDIM + h * DVH + c0;
        float4 a = *(const float4*)vp;
        float4 b2 = *(const float4*)(vp + 4);
        *(float4*)&stg[r >> 4][r & 15][c0]     = a;
        *(float4*)&stg[r >> 4][r & 15][c0 + 4] = b2;
    }
    __syncthreads();
    // P: 1 entry per thread
    {
        int t = tid >> 5, s = tid & 31;
        float a0 = 0.f;
        for (int k4 = 0; k4 < 128; k4 += 4) {
            float4 a = *(const float4*)&rt[t][k4];
            float4 b0 = *(const float4*)&kt[s][k4];
            a0 += a.x * b0.x + a.y * b0.y + a.z * b0.z + a.w * b0.w;
        }
        float u0 = ub[(size_t)(tok0 + t) * NHD + h];
        Ps[t][s] = (s < t) ? a0 : (s == t ? u0 : 0.f);
    }
    __syncthreads();
    int t0 = (tid >> 6) * 2;           // wave owns tokens t0, t0+1
    int c4 = (tid & 63) * 4;           // 64 lanes x 4 cols = full 256-col row
    float acc[2][4] = {};
    // intra-chunk: P @ v (from LDS)
    for (int s = 0; s < CK; s++) {
        float4 v0 = *(const float4*)&stg[s >> 4][s & 15][c4];
        float p0 = Ps[t0][s], p1 = Ps[t0 + 1][s];
        acc[0][0] += p0 * v0.x; acc[0][1] += p0 * v0.y;
        acc[0][2] += p0 * v0.z; acc[0][3] += p0 * v0.w;
        acc[1][0] += p1 * v0.x; acc[1][1] += p1 * v0.y;
        acc[1][2] += p1 * v0.z; acc[1][3] += p1 * v0.w;
    }
    // inter-chunk: r~ @ S, S tiled through LDS (each S byte read once from L2)
    size_t sbase = (size_t)(bh * NCK + ck) * 128 * DVH;
    int srow = tid >> 6;               // 0..15
    int scol = (tid & 63) * 4;
    float4 rg = *(const float4*)(Sb + sbase + (size_t)srow * DVH + scol);
    for (int tt = 0; tt < 8; tt++) {
        __syncthreads();               // prev tile (or v phase) reads complete
        *(float4*)&stg[0][srow][scol] = rg;
        if (tt < 7)
            rg = *(const float4*)(Sb + sbase + (size_t)((tt + 1) * 16 + srow) * DVH + scol);
        __syncthreads();               // tile staged
        #pragma unroll
        for (int q = 0; q < 16; q++) {
            int kk = tt * 16 + q;
            float4 s4 = *(const float4*)&stg[0][q][c4];
            float a0 = rt[t0][kk], a1 = rt[t0 + 1][kk];
            acc[0][0] += a0 * s4.x; acc[0][1] += a0 * s4.y;
            acc[0][2] += a0 * s4.z; acc[0][3] += a0 * s4.w;
            acc[1][0] += a1 * s4.x; acc[1][1] += a1 * s4.y;
            acc[1][2] += a1 * s4.z; acc[1][3] += a1 * s4.w;
        }
    }
    // groupnorm + affine + silu(g) gate, y f32 in place over v
    int cbase = h * DVH + c4;
    float4 gwA = *(const float4*)(gnw + cbase);
    float4 gbA = *(const float4*)(gnb + cbase);
    float gwv[4] = {gwA.x, gwA.y, gwA.z, gwA.w};
    float gbv[4] = {gbA.x, gbA.y, gbA.z, gbA.w};
    #pragma unroll
    for (int i = 0; i < 2; i++) {
        float sum = 0.f, sq = 0.f;
        #pragma unroll
        for (int jj = 0; jj < 4; jj++) {
            sum += acc[i][jj];
            sq  += acc[i][jj] * acc[i][jj];
        }
        #pragma unroll
        for (int m = 1; m < 64; m <<= 1) {
            sum += __shfl_xor(sum, m);
            sq  += __shfl_xor(sq, m);
        }
        float mean = sum * (1.f / DVH);
        float var = sq * (1.f / DVH) - mean * mean;
        float inv = rsqrtf(var + 1e-5f);
        size_t mrow = (size_t)(tok0 + t0 + i) * VDIM + cbase;
        float4 gA = *(const float4*)(gb_ + mrow);
        float gv[4] = {gA.x, gA.y, gA.z, gA.w};
        float o4[4];
        #pragma unroll
        for (int jj = 0; jj < 4; jj++) {
            float gg = gv[jj];
            float sig = 1.f / (1.f + __expf(-gg));
            o4[jj] = ((acc[i][jj] - mean) * inv * gwv[jj] + gbv[jj]) * (gg * sig);
        }
        *(float4*)(vb + mrow) = make_float4(o4[0], o4[1], o4[2], o4[3]);
    }
}

// ---------------------------------------------------------------------------
// Kernel 6: output GEMM, split precision. 64x128 tile. B-side staged via
// global_load_lds width=16 into LINEAR LDS [128][32] (512 chunks: each wave
// stages 2x64 chunks per buffer); A reg-staged (f2u hi/lo) into 40-pad LDS.
// ---------------------------------------------------------------------------
__global__ __launch_bounds__(256) void k_gemm_out(
    const float* __restrict__ A, const bf16* __restrict__ Bh,
    const bf16* __restrict__ Bl, float* __restrict__ C, int M, int N, int K)
{
    __shared__ unsigned short Ah[64 * 40];
    __shared__ unsigned short Al[64 * 40];
    __shared__ unsigned short Bhs[128 * 32];
    __shared__ unsigned short Bls[128 * 32];
    int tid = threadIdx.x;
    int bm = blockIdx.x * 64, bn = blockIdx.y * 128;
    int lane = tid & 63, w = tid >> 6;
    int wr = w >> 1, wc = w & 1;
    const unsigned short* Bh16 = (const unsigned short*)Bh;
    const unsigned short* Bl16 = (const unsigned short*)Bl;
    f32x4 acc[2][4];
    #pragma unroll
    for (int i = 0; i < 2; i++)
        #pragma unroll
        for (int j = 0; j < 4; j++)
            acc[i][j] = (f32x4){0.f, 0.f, 0.f, 0.f};
    int arow = tid >> 2, acol = (tid & 3) * 8;     // A: 64x32 f32, 8 per thread
    int fr = lane & 15, kb = (lane >> 4) * 8;
    int c0w = w * 128;
    for (int k0 = 0; k0 < K; k0 += 32) {
        float4 t4a = *(const float4*)(A + (size_t)(bm + arow) * K + k0 + acol);
        float4 t4b = *(const float4*)(A + (size_t)(bm + arow) * K + k0 + acol + 4);
        __syncthreads();                   // prev iteration frag reads complete
        #pragma unroll
        for (int q = 0; q < 2; q++) {
            int cb = c0w + q * 64;         // wave-uniform
            int c = cb + lane;
            int row = c >> 2, co = (c & 3) * 8;
            const unsigned short* gh2 = Bh16 + (size_t)(bn + row) * K + k0 + co;
            const unsigned short* gl2 = Bl16 + (size_t)(bn + row) * K + k0 + co;
            __builtin_amdgcn_global_load_lds(
                (const __attribute__((address_space(1))) void*)gh2,
                (__attribute__((address_space(3))) void*)(Bhs + cb * 8), 16, 0, 0);
            __builtin_amdgcn_global_load_lds(
                (const __attribute__((address_space(1))) void*)gl2,
                (__attribute__((address_space(3))) void*)(Bls + cb * 8), 16, 0, 0);
        }
        float av[8] = {t4a.x, t4a.y, t4a.z, t4a.w, t4b.x, t4b.y, t4b.z, t4b.w};
        alignas(16) unsigned short th[8], tl[8];
        #pragma unroll
        for (int q = 0; q < 8; q++) {
            unsigned short hu = f2u(av[q]);
            th[q] = hu;
            tl[q] = f2u(av[q] - u2f(hu));
        }
        *(uint4*)(Ah + arow * 40 + acol) = *(const uint4*)&th[0];
        *(uint4*)(Al + arow * 40 + acol) = *(const uint4*)&tl[0];
        __syncthreads();                   // gload_lds + A writes complete
        bf16x8 afh[2], afl[2], bfh[4], bfl[4];
        #pragma unroll
        for (int i = 0; i < 2; i++) {
            afh[i] = *(const bf16x8*)(Ah + (wr * 32 + i * 16 + fr) * 40 + kb);
            afl[i] = *(const bf16x8*)(Al + (wr * 32 + i * 16 + fr) * 40 + kb);
        }
        #pragma unroll
        for (int j = 0; j < 4; j++) {
            bfh[j] = *(const bf16x8*)(Bhs + (wc * 64 + j * 16 + fr) * 32 + kb);
            bfl[j] = *(const bf16x8*)(Bls + (wc * 64 + j * 16 + fr) * 32 + kb);
        }
        #pragma unroll
        for (int i = 0; i < 2; i++)
            #pragma unroll
            for (int j = 0; j < 4; j++) {
                acc[i][j] = __builtin_amdgcn_mfma_f32_16x16x32_bf16(afh[i], bfh[j], acc[i][j], 0, 0, 0);
                acc[i][j] = __builtin_amdgcn_mfma_f32_16x16x32_bf16(afl[i], bfh[j], acc[i][j], 0, 0, 0);
                acc[i][j] = __builtin_amdgcn_mfma_f32_16x16x32_bf16(afh[i], bfl[j], acc[i][j], 0, 0, 0);
            }
    }
    int er = (lane >> 4) * 4, ec = lane & 15;
    #pragma unroll
    for (int i = 0; i < 2; i++) {
        int gr = bm + wr * 32 + i * 16 + er;
        #pragma unroll
        for (int j = 0; j < 4; j++) {
            int gc = bn + wc * 64 + j * 16 + ec;
            #pragma unroll
            for (int q = 0; q < 4; q++)
                C[(size_t)(gr + q) * N + gc] = acc[i][j][q];
        }
    }
}

// ---------------------------------------------------------------------------
extern "C" void kernel_launch(void* const* d_in, const int* in_sizes, int n_in,
                              void* d_out, int out_size, void* d_ws, size_t ws_size,
                              hipStream_t stream)
{
    const float* h        = (const float*)d_in[0];
    const float* x_mu     = (const float*)d_in[1];
    const float* xl_w1    = (const float*)d_in[2];
    const float* xl_w2    = (const float*)d_in[3];
    const float* xl_b2    = (const float*)d_in[4];
    const float* x_out_w  = (const float*)d_in[5];
    const float* x_bias   = (const float*)d_in[6];
    const float* r_w      = (const float*)d_in[7];
    const float* w_w1     = (const float*)d_in[8];
    const float* w_w2     = (const float*)d_in[9];
    const float* w_b      = (const float*)d_in[10];
    const float* k_w      = (const float*)d_in[11];
    const float* v_w      = (const float*)d_in[12];
    const float* g_w      = (const float*)d_in[13];
    const float* bonus    = (const float*)d_in[14];
    const float* gn_w     = (const float*)d_in[15];
    const float* gn_b     = (const float*)d_in[16];
    const float* o_w      = (const float*)d_in[17];
    float* out = (float*)d_out;

    // Workspace overlay: total 35,733,504 floats = 142.9 MB (proven size)
    float* ws = (float*)d_ws;
    bf16*  wbf  = (bf16*)ws;                       // 8,388,608 bf16 = 4,194,304 slots
    float* rbuf = ws + 4194304;                    // 2,097,152
    float* vbuf = ws + 6291456;                    // 4,194,304 (y f32 in place later)
    float* gbuf = ws + 10485760;                   // 4,194,304
    float* kbuf = ws + 14680064;                   // 2,097,152
    float* ebuf = ws + 16777216;                   // 2,097,152
    float* ubuf = ws + 18874368;                   // 16,384
    float* Dbuf = ws + 18890752;                   // 65,536
    float* BIG  = ws + 18956288;                   // 16,777,216 (X phase / Mbuf)

    // weight hi/lo (bf16 element offsets within wbf)
    bf16* rwb_h = wbf;                  // 524,288
    bf16* kwb_h = wbf + 524288;
    bf16* vwb_h = wbf + 1048576;        // 1,048,576
    bf16* gwb_h = wbf + 2097152;
    bf16* owb_h = wbf + 3145728;
    bf16* rwb_l = wbf + 4194304;
    bf16* kwb_l = wbf + 4718592;
    bf16* vwb_l = wbf + 5242880;
    bf16* gwb_l = wbf + 6291456;
    bf16* owb_l = wbf + 7340032;

    // X phase inside BIG (each bf16 X = 2,097,152 float slots)
    float* Xw = BIG;                           // f32 [0 .. 4,194,304)
    bf16*  Xr = (bf16*)(BIG + 4194304);
    bf16*  Xk = (bf16*)(BIG + 6291456);
    bf16*  Xv = (bf16*)(BIG + 8388608);
    bf16*  Xg = (bf16*)(BIG + 10485760);
    float* x1   = BIG + 12582912;              // 655,360  (dead after mix)
    float* w1p  = BIG + 13238272;              // 2,097,152 (dead before Mbuf)
    float* Mbuf = BIG;                         // full 16,777,216 after X dead
    float* ybuf = vbuf;                        // y f32 in place over v

    // fused: x1 path (blocks 0..63) + f2b2 weight conversion (64..2111)
    k_x1f<<<64 + 2048, 256, 0, stream>>>(h, x_mu, xl_w1, xl_w2, xl_b2, x1,
                                         r_w, k_w, v_w, g_w, o_w,
                                         rwb_h, rwb_l, kwb_h, kwb_l,
                                         vwb_h, vwb_l, gwb_h, gwb_l,
                                         owb_h, owb_l);

    // mix: f32 w-slice + MFMA bf16 four-slice (xow LDS-staged)
    k_mixw<<<dim3(NTOK / 64, HH / 64), 256, 0, stream>>>(h, x1, x_out_w, x_bias, Xw);
    k_mix4<<<dim3(NTOK / 64, HH / 64), 256, 0, stream>>>(h, x1, x_out_w, x_bias,
                                                         Xr, Xk, Xv, Xg);

    // projections: ALL FOUR hi/lo MFMA GEMMs in one launch (128x128 tiles,
    // global_load_lds staging); split-K f32 w path
    k_gemm_hl4<<<dim3(NTOK / 128, VDIM / 128, 4), 256, 0, stream>>>(
        Xr, rwb_h, rwb_l, rbuf,
        Xk, kwb_h, kwb_l, kbuf,
        Xv, vwb_h, vwb_l, vbuf,
        Xg, gwb_h, gwb_l, gbuf, NTOK, HH);
    k_w1<<<dim3(NTOK / 64, WKS), 256, 0, stream>>>(Xw, w_w1, w1p);
    k_we<<<dim3(NTOK / 64, KDIM / 64), 256, 0, stream>>>(w1p, w_w2, w_b, ebuf);

    k_chunkA1<<<dim3(BB * NHD, NCK), 256, 0, stream>>>(ebuf, rbuf, kbuf, vbuf,
                                                       bonus, ubuf, Mbuf, Dbuf);
    k_chunkB<<<dim3(BB * NHD, NCK), 256, 0, stream>>>(Mbuf, Dbuf);
    k_chunkCG<<<dim3(BB * NHD, NCK), 1024, 0, stream>>>(rbuf, kbuf, vbuf, ubuf, Mbuf,
                                                        gbuf, gn_w, gn_b);

    k_gemm_out<<<dim3(NTOK / 64, HH / 128), 256, 0, stream>>>(ybuf, owb_h, owb_l, out, NTOK, HH, VDIM);
}